// Round 1
// baseline (1121.949 us; speedup 1.0000x reference)
//
#include <hip/hip_runtime.h>
#include <math.h>

#define B_  8
#define N_  1025
#define C_  512
#define H_  8
#define HD_ 64
#define M_  (B_ * N_)   // 8200

// ---------------------------------------------------------------------------
// Geometry bias collapses to an H x 32 x 32 table:
//   w = h = 33/32 constant  ->  dw = dh = 0
//   dx = log(max(|px_i - px_j|/33, 0.001)), px = cell/32 ; dy likewise, py = cell%32
// So bias[h][i][j] = tab[h][|px_i-px_j|][|py_i-py_j|]  (i,j are cell indices),
// padded with zeros at token row/col 0.
// ---------------------------------------------------------------------------
__global__ void bias_tab_kernel(const float* __restrict__ wg_w,
                                const float* __restrict__ wg_b,
                                float* __restrict__ tab) {
    int idx = blockIdx.x * blockDim.x + threadIdx.x;
    if (idx >= H_ * 32 * 32) return;
    int h = idx >> 10;
    int a = (idx >> 5) & 31;
    int b = idx & 31;
    float dx = logf(fmaxf((float)a * (1.0f / 33.0f), 0.001f));
    float dy = logf(fmaxf((float)b * (1.0f / 33.0f), 0.001f));
    const float* w = wg_w + h * 64;
    float acc = wg_b[h];
#pragma unroll
    for (int k = 0; k < 8; k++) {
        float f = powf(1000.0f, -(float)k * 0.125f);
        float X = 100.0f * dx * f;
        float Y = 100.0f * dy * f;
        acc += w[k]      * sinf(X);
        acc += w[8 + k]  * sinf(Y);
        acc += w[32 + k] * cosf(X);
        acc += w[40 + k] * cosf(Y);
        acc += w[48 + k] + w[56 + k];   // cos(0) channels for dw, dh
    }
    tab[idx] = logf(fmaxf(fmaxf(acc, 0.0f), 1e-6f));
}

// ---------------------------------------------------------------------------
// Tiled fp32 GEMM  C[M][Nn] = A[M][K] * W[Nn][K]^T
// BM=BN=64, BK=16, 256 threads, 4x4 micro-tile per thread.
// ---------------------------------------------------------------------------
#define BM 64
#define BN 64
#define BK 16

// QKV: A = x [8200][512], W = qkv_w [1536][512]; scatter to q/k/v [B][H][N][64]
__global__ __launch_bounds__(256) void gemm_qkv(const float* __restrict__ A,
                                                const float* __restrict__ W,
                                                float* __restrict__ q,
                                                float* __restrict__ k,
                                                float* __restrict__ v) {
    __shared__ float As[BK][BM];
    __shared__ float Bs[BK][BN];
    const int K = C_;
    int tid = threadIdx.x;
    int m0 = blockIdx.y * BM;
    int n0 = blockIdx.x * BN;
    int tm = tid >> 4;        // 0..15
    int tn = tid & 15;        // 0..15
    int lr = tid >> 2;        // 0..63 (row within tile for staging)
    int lk = (tid & 3) << 2;  // 0,4,8,12
    float acc[4][4] = {};

    for (int k0 = 0; k0 < K; k0 += BK) {
        int am = m0 + lr;
        float4 av = (am < M_) ? *(const float4*)(A + (size_t)am * K + k0 + lk)
                              : make_float4(0.f, 0.f, 0.f, 0.f);
        float4 bv = *(const float4*)(W + (size_t)(n0 + lr) * K + k0 + lk);
        __syncthreads();
        As[lk + 0][lr] = av.x; As[lk + 1][lr] = av.y;
        As[lk + 2][lr] = av.z; As[lk + 3][lr] = av.w;
        Bs[lk + 0][lr] = bv.x; Bs[lk + 1][lr] = bv.y;
        Bs[lk + 2][lr] = bv.z; Bs[lk + 3][lr] = bv.w;
        __syncthreads();
#pragma unroll
        for (int kk = 0; kk < BK; kk++) {
            float a[4], b[4];
            *(float4*)a = *(const float4*)&As[kk][tm << 2];
            *(float4*)b = *(const float4*)&Bs[kk][tn << 2];
#pragma unroll
            for (int mi = 0; mi < 4; mi++)
#pragma unroll
                for (int ni = 0; ni < 4; ni++)
                    acc[mi][ni] += a[mi] * b[ni];
        }
    }

    // n0 is 64-aligned: whole block maps to one (which, head), d = n - n0 + tn*4
    int which = n0 >> 9;
    int h = (n0 >> 6) & 7;
    float* dst = (which == 0) ? q : (which == 1) ? k : v;
#pragma unroll
    for (int mi = 0; mi < 4; mi++) {
        int m = m0 + (tm << 2) + mi;
        if (m < M_) {
            int bb = m / N_;
            int i  = m - bb * N_;
            float4 vv = make_float4(acc[mi][0], acc[mi][1], acc[mi][2], acc[mi][3]);
            *(float4*)(dst + (size_t)(((bb * H_ + h) * N_ + i)) * HD_ + (tn << 2)) = vv;
        }
    }
}

// Proj: A = attn_out [8200][512], W = proj_w [512][512], +proj_b -> out
__global__ __launch_bounds__(256) void gemm_proj(const float* __restrict__ A,
                                                 const float* __restrict__ W,
                                                 const float* __restrict__ bias,
                                                 float* __restrict__ out) {
    __shared__ float As[BK][BM];
    __shared__ float Bs[BK][BN];
    const int K = C_;
    int tid = threadIdx.x;
    int m0 = blockIdx.y * BM;
    int n0 = blockIdx.x * BN;
    int tm = tid >> 4;
    int tn = tid & 15;
    int lr = tid >> 2;
    int lk = (tid & 3) << 2;
    float acc[4][4] = {};

    for (int k0 = 0; k0 < K; k0 += BK) {
        int am = m0 + lr;
        float4 av = (am < M_) ? *(const float4*)(A + (size_t)am * K + k0 + lk)
                              : make_float4(0.f, 0.f, 0.f, 0.f);
        float4 bv = *(const float4*)(W + (size_t)(n0 + lr) * K + k0 + lk);
        __syncthreads();
        As[lk + 0][lr] = av.x; As[lk + 1][lr] = av.y;
        As[lk + 2][lr] = av.z; As[lk + 3][lr] = av.w;
        Bs[lk + 0][lr] = bv.x; Bs[lk + 1][lr] = bv.y;
        Bs[lk + 2][lr] = bv.z; Bs[lk + 3][lr] = bv.w;
        __syncthreads();
#pragma unroll
        for (int kk = 0; kk < BK; kk++) {
            float a[4], b[4];
            *(float4*)a = *(const float4*)&As[kk][tm << 2];
            *(float4*)b = *(const float4*)&Bs[kk][tn << 2];
#pragma unroll
            for (int mi = 0; mi < 4; mi++)
#pragma unroll
                for (int ni = 0; ni < 4; ni++)
                    acc[mi][ni] += a[mi] * b[ni];
        }
    }

    float bvals[4];
    *(float4*)bvals = *(const float4*)(bias + n0 + (tn << 2));
#pragma unroll
    for (int mi = 0; mi < 4; mi++) {
        int m = m0 + (tm << 2) + mi;
        if (m < M_) {
            float4 vv = make_float4(acc[mi][0] + bvals[0], acc[mi][1] + bvals[1],
                                    acc[mi][2] + bvals[2], acc[mi][3] + bvals[3]);
            *(float4*)(out + (size_t)m * C_ + n0 + (tn << 2)) = vv;
        }
    }
}

// ---------------------------------------------------------------------------
// Flash-style attention. grid = (ceil(N/128), H, B), 256 threads.
// 2 threads per query row (each owns 32 of the 64 dims). Online softmax with
// per-32-j-chunk rescaling. Bias via the 32x32 per-head LDS table.
// ---------------------------------------------------------------------------
#define ROWS 128
#define JC   32

__global__ __launch_bounds__(256) void attn_kernel(const float* __restrict__ qg,
                                                   const float* __restrict__ kg,
                                                   const float* __restrict__ vg,
                                                   const float* __restrict__ tab,
                                                   float* __restrict__ og) {
    __shared__ float Ks[JC][HD_];
    __shared__ float Vs[JC][HD_];
    __shared__ float Sc[ROWS][JC];
    __shared__ float tabs[1024];

    int tile = blockIdx.x, h = blockIdx.y, b = blockIdx.z;
    int tid = threadIdx.x;
    int rl = tid >> 1;                 // row within block 0..127
    int hf = tid & 1;                  // which 32-dim half
    int r = tile * ROWS + rl;          // token (query) index
    const float scale = 0.125f;        // 64^-0.5

    for (int t = tid; t < 1024; t += 256) tabs[t] = tab[h * 1024 + t];

    const float* qp = qg + (size_t)(b * H_ + h) * N_ * HD_;
    const float* kp = kg + (size_t)(b * H_ + h) * N_ * HD_;
    const float* vp = vg + (size_t)(b * H_ + h) * N_ * HD_;

    bool rvalid = (r < N_);
    float qreg[32];
    if (rvalid) {
        const float4* qrow = (const float4*)(qp + (size_t)r * HD_ + hf * 32);
#pragma unroll
        for (int d4 = 0; d4 < 8; d4++) {
            float4 t4 = qrow[d4];
            qreg[d4 * 4 + 0] = t4.x * scale; qreg[d4 * 4 + 1] = t4.y * scale;
            qreg[d4 * 4 + 2] = t4.z * scale; qreg[d4 * 4 + 3] = t4.w * scale;
        }
    } else {
#pragma unroll
        for (int d = 0; d < 32; d++) qreg[d] = 0.f;
    }

    int ii = r - 1;
    int di = ii >> 5, mi = ii & 31;    // only meaningful when r >= 1

    float o[32];
#pragma unroll
    for (int d = 0; d < 32; d++) o[d] = 0.f;
    float m = -1e30f, l = 0.f;

    for (int j0 = 0; j0 < N_; j0 += JC) {
        int cnt = min(JC, N_ - j0);
        __syncthreads();   // previous iteration done with Vs/Sc
        for (int t = tid; t < cnt * (HD_ / 4); t += 256) {
            ((float4*)Ks)[t] = ((const float4*)(kp + (size_t)j0 * HD_))[t];
            ((float4*)Vs)[t] = ((const float4*)(vp + (size_t)j0 * HD_))[t];
        }
        __syncthreads();

        // pass A: scores for my row
        for (int j = 0; j < cnt; j++) {
            float s = 0.f;
            const float4* krow = (const float4*)&Ks[j][hf * 32];
#pragma unroll
            for (int d4 = 0; d4 < 8; d4++) {
                float4 kv = krow[d4];
                s += qreg[d4 * 4 + 0] * kv.x + qreg[d4 * 4 + 1] * kv.y +
                     qreg[d4 * 4 + 2] * kv.z + qreg[d4 * 4 + 3] * kv.w;
            }
            s += __shfl_xor(s, 1);
            if (hf == 0) {
                float bia = 0.f;
                int jj = j0 + j - 1;
                if (rvalid && r > 0 && jj >= 0) {
                    int dj = jj >> 5, mj = jj & 31;
                    int da = di - dj; if (da < 0) da = -da;
                    int db = mi - mj; if (db < 0) db = -db;
                    bia = tabs[da * 32 + db];
                }
                Sc[rl][j] = s + bia;
            }
        }
        __syncthreads();

        // pass B: online softmax + PV accumulate
        float mc = -1e30f;
        for (int j = 0; j < cnt; j++) mc = fmaxf(mc, Sc[rl][j]);
        float mnew = fmaxf(m, mc);
        float corr = __expf(m - mnew);
        l *= corr;
#pragma unroll
        for (int d = 0; d < 32; d++) o[d] *= corr;
        for (int j = 0; j < cnt; j++) {
            float p = __expf(Sc[rl][j] - mnew);
            l += p;
            const float4* vrow = (const float4*)&Vs[j][hf * 32];
#pragma unroll
            for (int d4 = 0; d4 < 8; d4++) {
                float4 vv = vrow[d4];
                o[d4 * 4 + 0] += p * vv.x; o[d4 * 4 + 1] += p * vv.y;
                o[d4 * 4 + 2] += p * vv.z; o[d4 * 4 + 3] += p * vv.w;
            }
        }
        m = mnew;
    }

    if (rvalid) {
        float inv = 1.0f / l;
        float* orow = og + (size_t)(b * N_ + r) * C_ + h * HD_ + hf * 32;
#pragma unroll
        for (int d4 = 0; d4 < 8; d4++) {
            float4 vv = make_float4(o[d4 * 4 + 0] * inv, o[d4 * 4 + 1] * inv,
                                    o[d4 * 4 + 2] * inv, o[d4 * 4 + 3] * inv);
            ((float4*)orow)[d4] = vv;
        }
    }
}

// ---------------------------------------------------------------------------
extern "C" void kernel_launch(void* const* d_in, const int* in_sizes, int n_in,
                              void* d_out, int out_size, void* d_ws, size_t ws_size,
                              hipStream_t stream) {
    const float* x      = (const float*)d_in[0];
    const float* qkv_w  = (const float*)d_in[1];
    const float* proj_w = (const float*)d_in[2];
    const float* proj_b = (const float*)d_in[3];
    const float* wg_w   = (const float*)d_in[4];
    const float* wg_b   = (const float*)d_in[5];
    float* out = (float*)d_out;

    char* ws = (char*)d_ws;
    float* tab = (float*)ws;                         // 8192 floats (32 KB)
    float* q   = (float*)(ws + 32 * 1024);
    const size_t per = (size_t)B_ * H_ * N_ * HD_;   // 4,198,400 floats
    float* k   = q + per;
    float* v   = k + per;
    float* o   = v + per;                            // [B][N][C] attn output

    bias_tab_kernel<<<32, 256, 0, stream>>>(wg_w, wg_b, tab);
    gemm_qkv<<<dim3((3 * C_) / BN, (M_ + BM - 1) / BM), 256, 0, stream>>>(x, qkv_w, q, k, v);
    attn_kernel<<<dim3((N_ + ROWS - 1) / ROWS, H_, B_), 256, 0, stream>>>(q, k, v, tab, o);
    gemm_proj<<<dim3(C_ / BN, (M_ + BM - 1) / BM), 256, 0, stream>>>(o, proj_w, proj_b, out);
}

// Round 2
// 503.295 us; speedup vs baseline: 2.2292x; 2.2292x over previous
//
#include <hip/hip_runtime.h>
#include <hip/hip_bf16.h>
#include <math.h>

#define B_  8
#define N_  1025
#define C_  512
#define H_  8
#define HD_ 64
#define M_  (B_ * N_)   // 8200
#define NP_ 1032        // padded token stride for vt (multiple of 8)

typedef __attribute__((ext_vector_type(8))) short short8;
typedef __attribute__((ext_vector_type(4))) float f32x4;

__device__ inline unsigned short bf16u(float x) {
    __hip_bfloat16 t = __float2bfloat16(x);
    return *(unsigned short*)&t;
}
__device__ inline unsigned pack_bf16x2(float lo, float hi) {
    return ((unsigned)bf16u(hi) << 16) | bf16u(lo);
}
__device__ inline void load_lds16(const void* g, void* l) {
    __builtin_amdgcn_global_load_lds(
        (const __attribute__((address_space(1))) unsigned int*)g,
        (__attribute__((address_space(3))) unsigned int*)l, 16, 0, 0);
}

// ---------------------------------------------------------------------------
// Geometry bias collapses to an H x 32 x 32 table (dw=dh=0; |dpx|,|dpy| only).
// ---------------------------------------------------------------------------
__global__ void bias_tab_kernel(const float* __restrict__ wg_w,
                                const float* __restrict__ wg_b,
                                float* __restrict__ tab) {
    int idx = blockIdx.x * blockDim.x + threadIdx.x;
    if (idx >= H_ * 32 * 32) return;
    int h = idx >> 10;
    int a = (idx >> 5) & 31;
    int b = idx & 31;
    float dx = logf(fmaxf((float)a * (1.0f / 33.0f), 0.001f));
    float dy = logf(fmaxf((float)b * (1.0f / 33.0f), 0.001f));
    const float* w = wg_w + h * 64;
    float acc = wg_b[h];
#pragma unroll
    for (int k = 0; k < 8; k++) {
        float f = powf(1000.0f, -(float)k * 0.125f);
        float X = 100.0f * dx * f;
        float Y = 100.0f * dy * f;
        acc += w[k]      * sinf(X);
        acc += w[8 + k]  * sinf(Y);
        acc += w[32 + k] * cosf(X);
        acc += w[40 + k] * cosf(Y);
        acc += w[48 + k] + w[56 + k];
    }
    tab[idx] = logf(fmaxf(fmaxf(acc, 0.0f), 1e-6f));
}

// ---------------------------------------------------------------------------
// QKV GEMM (fp32 compute): x[8200][512] @ qkv_w[1536][512]^T.
// Emits: q bf16 [bh][tok][64] pre-scaled by 0.125; k bf16 [bh][tok][64];
//        vt bf16 [bh][dim][NP_] (transposed).
// ---------------------------------------------------------------------------
#define BM 64
#define BN 64
#define BK 16

__global__ __launch_bounds__(256) void gemm_qkv(const float* __restrict__ A,
                                                const float* __restrict__ W,
                                                unsigned short* __restrict__ qg,
                                                unsigned short* __restrict__ kg,
                                                unsigned short* __restrict__ vtg) {
    __shared__ float As[BK][BM];
    __shared__ float Bs[BK][BN];
    const int K = C_;
    int tid = threadIdx.x;
    int m0 = blockIdx.y * BM;
    int n0 = blockIdx.x * BN;
    int tm = tid >> 4;
    int tn = tid & 15;
    int lr = tid >> 2;
    int lk = (tid & 3) << 2;
    float acc[4][4] = {};

    for (int k0 = 0; k0 < K; k0 += BK) {
        int am = m0 + lr;
        float4 av = (am < M_) ? *(const float4*)(A + (size_t)am * K + k0 + lk)
                              : make_float4(0.f, 0.f, 0.f, 0.f);
        float4 bv = *(const float4*)(W + (size_t)(n0 + lr) * K + k0 + lk);
        __syncthreads();
        As[lk + 0][lr] = av.x; As[lk + 1][lr] = av.y;
        As[lk + 2][lr] = av.z; As[lk + 3][lr] = av.w;
        Bs[lk + 0][lr] = bv.x; Bs[lk + 1][lr] = bv.y;
        Bs[lk + 2][lr] = bv.z; Bs[lk + 3][lr] = bv.w;
        __syncthreads();
#pragma unroll
        for (int kk = 0; kk < BK; kk++) {
            float a[4], b[4];
            *(float4*)a = *(const float4*)&As[kk][tm << 2];
            *(float4*)b = *(const float4*)&Bs[kk][tn << 2];
#pragma unroll
            for (int mi = 0; mi < 4; mi++)
#pragma unroll
                for (int ni = 0; ni < 4; ni++)
                    acc[mi][ni] += a[mi] * b[ni];
        }
    }

    int which = n0 >> 9;
    int h = (n0 >> 6) & 7;
    if (which < 2) {
        unsigned short* dst = (which == 0) ? qg : kg;
        float sc = (which == 0) ? 0.125f : 1.0f;   // fold attention scale into q
#pragma unroll
        for (int mi = 0; mi < 4; mi++) {
            int m = m0 + (tm << 2) + mi;
            if (m < M_) {
                int bb = m / N_;
                int i  = m - bb * N_;
                ushort4 pk;
                pk.x = bf16u(acc[mi][0] * sc); pk.y = bf16u(acc[mi][1] * sc);
                pk.z = bf16u(acc[mi][2] * sc); pk.w = bf16u(acc[mi][3] * sc);
                *(ushort4*)(dst + (size_t)((bb * H_ + h) * (size_t)N_ + i) * HD_ + (tn << 2)) = pk;
            }
        }
    } else {
        // vt[bh][dim][token], scalar stores (token alignment is irregular)
        int mbase = m0 + (tm << 2);
#pragma unroll
        for (int ni = 0; ni < 4; ni++) {
            int dim = (tn << 2) + ni;
#pragma unroll
            for (int mi = 0; mi < 4; mi++) {
                int m = mbase + mi;
                if (m < M_) {
                    int bb = m / N_;
                    int i  = m - bb * N_;
                    vtg[((size_t)(bb * H_ + h) * HD_ + dim) * NP_ + i] = bf16u(acc[mi][ni]);
                }
            }
        }
    }
}

// ---------------------------------------------------------------------------
// Proj GEMM (fp32): o[8200][512] @ proj_w[512][512]^T + proj_b
// ---------------------------------------------------------------------------
__global__ __launch_bounds__(256) void gemm_proj(const float* __restrict__ A,
                                                 const float* __restrict__ W,
                                                 const float* __restrict__ bias,
                                                 float* __restrict__ out) {
    __shared__ float As[BK][BM];
    __shared__ float Bs[BK][BN];
    const int K = C_;
    int tid = threadIdx.x;
    int m0 = blockIdx.y * BM;
    int n0 = blockIdx.x * BN;
    int tm = tid >> 4;
    int tn = tid & 15;
    int lr = tid >> 2;
    int lk = (tid & 3) << 2;
    float acc[4][4] = {};

    for (int k0 = 0; k0 < K; k0 += BK) {
        int am = m0 + lr;
        float4 av = (am < M_) ? *(const float4*)(A + (size_t)am * K + k0 + lk)
                              : make_float4(0.f, 0.f, 0.f, 0.f);
        float4 bv = *(const float4*)(W + (size_t)(n0 + lr) * K + k0 + lk);
        __syncthreads();
        As[lk + 0][lr] = av.x; As[lk + 1][lr] = av.y;
        As[lk + 2][lr] = av.z; As[lk + 3][lr] = av.w;
        Bs[lk + 0][lr] = bv.x; Bs[lk + 1][lr] = bv.y;
        Bs[lk + 2][lr] = bv.z; Bs[lk + 3][lr] = bv.w;
        __syncthreads();
#pragma unroll
        for (int kk = 0; kk < BK; kk++) {
            float a[4], b[4];
            *(float4*)a = *(const float4*)&As[kk][tm << 2];
            *(float4*)b = *(const float4*)&Bs[kk][tn << 2];
#pragma unroll
            for (int mi = 0; mi < 4; mi++)
#pragma unroll
                for (int ni = 0; ni < 4; ni++)
                    acc[mi][ni] += a[mi] * b[ni];
        }
    }

    float bvals[4];
    *(float4*)bvals = *(const float4*)(bias + n0 + (tn << 2));
#pragma unroll
    for (int mi = 0; mi < 4; mi++) {
        int m = m0 + (tm << 2) + mi;
        if (m < M_) {
            float4 vv = make_float4(acc[mi][0] + bvals[0], acc[mi][1] + bvals[1],
                                    acc[mi][2] + bvals[2], acc[mi][3] + bvals[3]);
            *(float4*)(out + (size_t)m * C_ + n0 + (tn << 2)) = vv;
        }
    }
}

// ---------------------------------------------------------------------------
// MFMA flash attention. grid = (ceil(N/128), H, B), 512 threads = 8 waves.
// Wave w owns q rows [tile*128 + w*16, +16). 32-key chunks staged in LDS.
//   Kf: fragment-ordered, block b = oct*32+key holds K[key][oct*8..+7]
//       (lane-linear -> global_load_lds width 16, conflict-free b128 reads)
//   Vt: [dim][40] bf16 (pad 32->40 keys: frag-read 2-way max = free)
//   Pl: per-wave P [16 rows][32 keys] bf16 round-trip for C->A layout
// ---------------------------------------------------------------------------
#define TQ 128
#define JC 32

__global__ __launch_bounds__(512) void attn_mfma(const unsigned short* __restrict__ qg,
                                                 const unsigned short* __restrict__ kg,
                                                 const unsigned short* __restrict__ vtg,
                                                 const float* __restrict__ tab,
                                                 float* __restrict__ og) {
    __shared__ __align__(16) unsigned short Kf[32 * 64];     // 4 KB
    __shared__ __align__(16) unsigned short Vt[64 * 40];     // 5 KB
    __shared__ __align__(16) unsigned short Pl[8][16 * 32];  // 8 KB
    __shared__ float tabs[1024];                             // 4 KB

    int tid = threadIdx.x;
    int wave = tid >> 6, lane = tid & 63;
    int quad = lane >> 4, l16 = lane & 15;
    int tile = blockIdx.x, h = blockIdx.y, b = blockIdx.z;
    int bh = b * H_ + h;

    const unsigned short* qp = qg  + (size_t)bh * N_ * HD_;
    const unsigned short* kp = kg  + (size_t)bh * N_ * HD_;
    const unsigned short* vp = vtg + (size_t)bh * HD_ * NP_;

    for (int t = tid; t < 1024; t += 512) tabs[t] = tab[h * 1024 + t];

    // Q fragments (A-layout): row = tile*TQ + wave*16 + l16, k = c*32 + quad*8 + j
    int row_l = tile * TQ + wave * 16 + l16;
    int rowc = min(row_l, N_ - 1);
    short8 qf[2];
    qf[0] = *(const short8*)(qp + (size_t)rowc * HD_ + quad * 8);
    qf[1] = *(const short8*)(qp + (size_t)rowc * HD_ + 32 + quad * 8);

    // C-layout rows owned by this lane: r0c + reg (reg=0..3)
    int r0c = tile * TQ + wave * 16 + quad * 4;
    // bias decomposition for my rows (valid only when row>=1)
    float m_i[4], l_i[4];
    f32x4 o_acc[4];
    const f32x4 zero4 = {0.f, 0.f, 0.f, 0.f};
#pragma unroll
    for (int r = 0; r < 4; r++) { m_i[r] = -1e30f; l_i[r] = 0.f; o_acc[r] = zero4; }

    for (int j0 = 0; j0 < N_; j0 += JC) {
        __syncthreads();
        if (wave < 4) {
            // stage K chunk: thread t64 = wave*64+lane -> block b = t64 (lane-linear)
            int t64 = wave * 64 + lane;
            int key = t64 & 31, oct = t64 >> 5;
            int kk = min(j0 + key, N_ - 1);
            load_lds16(kp + (size_t)kk * HD_ + oct * 8, &Kf[wave * 512]);
        } else {
            // stage Vt chunk: t2 in 0..255 -> dim = t2>>2, koct = t2&3
            int t2 = tid - 256;
            int dim = t2 >> 2, koct = t2 & 3;
            uint4 d = *(const uint4*)(vp + (size_t)dim * NP_ + j0 + koct * 8);
            *(uint4*)&Vt[dim * 40 + koct * 8] = d;
        }
        __syncthreads();

        // ---- QK^T: S[16 rows][32 keys] = two g-tiles of 16x16 ----
        f32x4 s[2];
#pragma unroll
        for (int g = 0; g < 2; g++) {
            short8 kb0 = *(const short8*)&Kf[((0 * 4 + quad) * 32 + g * 16 + l16) * 8];
            short8 kb1 = *(const short8*)&Kf[((1 * 4 + quad) * 32 + g * 16 + l16) * 8];
            f32x4 t = __builtin_amdgcn_mfma_f32_16x16x32_bf16(qf[0], kb0, zero4, 0, 0, 0);
            s[g]     = __builtin_amdgcn_mfma_f32_16x16x32_bf16(qf[1], kb1, t,     0, 0, 0);
        }

        // ---- bias + mask ----
#pragma unroll
        for (int g = 0; g < 2; g++) {
            int jj = j0 + g * 16 + l16;     // key token
#pragma unroll
            for (int reg = 0; reg < 4; reg++) {
                int r = r0c + reg;          // query token
                float bia;
                if (r >= N_ || jj >= N_)      bia = -1e30f;
                else if (r == 0 || jj == 0)   bia = 0.f;
                else {
                    int ri = r - 1, ji = jj - 1;
                    int da = (ri >> 5) - (ji >> 5); da = da < 0 ? -da : da;
                    int db = (ri & 31) - (ji & 31); db = db < 0 ? -db : db;
                    bia = tabs[da * 32 + db];
                }
                s[g][reg] += bia;
            }
        }

        // ---- online softmax ----
        float mc[4];
#pragma unroll
        for (int reg = 0; reg < 4; reg++) mc[reg] = fmaxf(s[0][reg], s[1][reg]);
#pragma unroll
        for (int off = 1; off < 16; off <<= 1)
#pragma unroll
            for (int reg = 0; reg < 4; reg++)
                mc[reg] = fmaxf(mc[reg], __shfl_xor(mc[reg], off));

        float alpha[4];
#pragma unroll
        for (int reg = 0; reg < 4; reg++) {
            float mnew = fmaxf(m_i[reg], mc[reg]);
            alpha[reg] = __expf(m_i[reg] - mnew);
            m_i[reg] = mnew;
        }
        float ps0[4], ps1[4], lsum[4];
#pragma unroll
        for (int reg = 0; reg < 4; reg++) {
            ps0[reg] = __expf(s[0][reg] - m_i[reg]);
            ps1[reg] = __expf(s[1][reg] - m_i[reg]);
            lsum[reg] = ps0[reg] + ps1[reg];
        }
#pragma unroll
        for (int off = 1; off < 16; off <<= 1)
#pragma unroll
            for (int reg = 0; reg < 4; reg++)
                lsum[reg] += __shfl_xor(lsum[reg], off);
#pragma unroll
        for (int reg = 0; reg < 4; reg++)
            l_i[reg] = l_i[reg] * alpha[reg] + lsum[reg];
#pragma unroll
        for (int g2 = 0; g2 < 4; g2++)
#pragma unroll
            for (int reg = 0; reg < 4; reg++)
                o_acc[g2][reg] *= alpha[reg];

        // ---- P -> LDS (C-layout -> A-layout round trip) ----
        // even lane writes its g0 col-pair, odd lane writes its g1 col-pair
        {
            int par = lane & 1;
            int colp = par * 16 + (l16 & ~1);
#pragma unroll
            for (int reg = 0; reg < 4; reg++) {
                float o0 = __shfl_xor(ps0[reg], 1);
                float o1 = __shfl_xor(ps1[reg], 1);
                float va = par ? o1 : ps0[reg];
                float vb = par ? ps1[reg] : o0;
                *(unsigned*)&Pl[wave][(quad * 4 + reg) * 32 + colp] = pack_bf16x2(va, vb);
            }
        }
        short8 pf = *(const short8*)&Pl[wave][l16 * 32 + quad * 8];

        // ---- PV: O[16 rows][64 dims] += P @ V ----
#pragma unroll
        for (int g2 = 0; g2 < 4; g2++) {
            short8 vb = *(const short8*)&Vt[(g2 * 16 + l16) * 40 + quad * 8];
            o_acc[g2] = __builtin_amdgcn_mfma_f32_16x16x32_bf16(pf, vb, o_acc[g2], 0, 0, 0);
        }
    }

    // ---- store (C-layout): row = r0c+reg, dim = g2*16 + l16 ----
#pragma unroll
    for (int reg = 0; reg < 4; reg++) {
        int r = r0c + reg;
        if (r < N_) {
            float inv = 1.0f / l_i[reg];
            float* orow = og + ((size_t)b * N_ + r) * C_ + h * HD_ + l16;
#pragma unroll
            for (int g2 = 0; g2 < 4; g2++)
                orow[g2 * 16] = o_acc[g2][reg] * inv;
        }
    }
}

// ---------------------------------------------------------------------------
extern "C" void kernel_launch(void* const* d_in, const int* in_sizes, int n_in,
                              void* d_out, int out_size, void* d_ws, size_t ws_size,
                              hipStream_t stream) {
    const float* x      = (const float*)d_in[0];
    const float* qkv_w  = (const float*)d_in[1];
    const float* proj_w = (const float*)d_in[2];
    const float* proj_b = (const float*)d_in[3];
    const float* wg_w   = (const float*)d_in[4];
    const float* wg_b   = (const float*)d_in[5];
    float* out = (float*)d_out;

    char* ws = (char*)d_ws;
    float* tab = (float*)ws;                                  // 32 KB
    unsigned short* qb = (unsigned short*)(ws + 32 * 1024);
    const size_t per = (size_t)B_ * H_ * N_ * HD_;            // 4,198,400 bf16
    unsigned short* kb = qb + per;
    unsigned short* vtb = kb + per;
    const size_t vtsz = (size_t)B_ * H_ * HD_ * NP_;          // 4,227,072 bf16
    float* o = (float*)(vtb + vtsz);                          // [B][N][C] fp32

    bias_tab_kernel<<<32, 256, 0, stream>>>(wg_w, wg_b, tab);
    gemm_qkv<<<dim3((3 * C_) / BN, (M_ + BM - 1) / BM), 256, 0, stream>>>(x, qkv_w, qb, kb, vtb);
    attn_mfma<<<dim3((N_ + TQ - 1) / TQ, H_, B_), 512, 0, stream>>>(qb, kb, vtb, tab, o);
    gemm_proj<<<dim3(C_ / BN, (M_ + BM - 1) / BM), 256, 0, stream>>>(o, proj_w, proj_b, out);
}

// Round 3
// 295.585 us; speedup vs baseline: 3.7957x; 1.7027x over previous
//
#include <hip/hip_runtime.h>
#include <hip/hip_bf16.h>
#include <math.h>

#define B_  8
#define N_  1025
#define C_  512
#define H_  8
#define HD_ 64
#define M_  (B_ * N_)   // 8200

typedef __attribute__((ext_vector_type(8))) short short8;
typedef __attribute__((ext_vector_type(4))) float f32x4;

__device__ inline unsigned short bf16u(float x) {
    __hip_bfloat16 t = __float2bfloat16(x);
    return *(unsigned short*)&t;
}
__device__ inline unsigned pack_bf16x2(float lo, float hi) {
    return ((unsigned)bf16u(hi) << 16) | bf16u(lo);
}
__device__ inline void load_lds16(const void* g, void* l) {
    __builtin_amdgcn_global_load_lds(
        (const __attribute__((address_space(1))) unsigned int*)g,
        (__attribute__((address_space(3))) unsigned int*)l, 16, 0, 0);
}

// ---------------------------------------------------------------------------
// fp32 -> bf16 cast (x, qkv_w, proj_w)
// ---------------------------------------------------------------------------
__global__ void cast_bf16_kernel(const float* __restrict__ src,
                                 unsigned short* __restrict__ dst, int n) {
    int i4 = (blockIdx.x * blockDim.x + threadIdx.x) * 4;
    if (i4 + 3 < n) {
        float4 v = *(const float4*)(src + i4);
        ushort4 p;
        p.x = bf16u(v.x); p.y = bf16u(v.y); p.z = bf16u(v.z); p.w = bf16u(v.w);
        *(ushort4*)(dst + i4) = p;
    }
}

// ---------------------------------------------------------------------------
// Geometry bias collapses to an H x 32 x 32 table (dw=dh=0; |dpx|,|dpy| only).
// ---------------------------------------------------------------------------
__global__ void bias_tab_kernel(const float* __restrict__ wg_w,
                                const float* __restrict__ wg_b,
                                float* __restrict__ tab) {
    int idx = blockIdx.x * blockDim.x + threadIdx.x;
    if (idx >= H_ * 32 * 32) return;
    int h = idx >> 10;
    int a = (idx >> 5) & 31;
    int b = idx & 31;
    float dx = logf(fmaxf((float)a * (1.0f / 33.0f), 0.001f));
    float dy = logf(fmaxf((float)b * (1.0f / 33.0f), 0.001f));
    const float* w = wg_w + h * 64;
    float acc = wg_b[h];
#pragma unroll
    for (int k = 0; k < 8; k++) {
        float f = powf(1000.0f, -(float)k * 0.125f);
        float X = 100.0f * dx * f;
        float Y = 100.0f * dy * f;
        acc += w[k]      * sinf(X);
        acc += w[8 + k]  * sinf(Y);
        acc += w[32 + k] * cosf(X);
        acc += w[40 + k] * cosf(Y);
        acc += w[48 + k] + w[56 + k];
    }
    tab[idx] = logf(fmaxf(fmaxf(acc, 0.0f), 1e-6f));
}

// ---------------------------------------------------------------------------
// MFMA GEMM core: C[M][Nn] = A[M][K] @ W[Nn][K]^T, bf16 in, fp32 acc.
// 128x128 tile, BK=32, 256 threads = 4 waves (2x2 of 64x64), m97 staging.
// ---------------------------------------------------------------------------
#define GK 512

// QKV variant: scatter to q (x0.125) / k / v, all bf16 [bh][tok][64]
__global__ __launch_bounds__(256) void gemm_qkv_mfma(
        const unsigned short* __restrict__ A, const unsigned short* __restrict__ W,
        unsigned short* __restrict__ qb, unsigned short* __restrict__ kb,
        unsigned short* __restrict__ vb) {
    __shared__ __align__(16) unsigned short As[128 * 32];
    __shared__ __align__(16) unsigned short Bs[128 * 32];
    int tid = threadIdx.x;
    int w = tid >> 6, lane = tid & 63;
    int quad = lane >> 4, l16 = lane & 15;
    int m0 = blockIdx.y * 128;
    int n0 = blockIdx.x * 128;
    int wr = (w >> 1) * 64, wc = (w & 1) * 64;

    // staging chunk ids (16B = 8 bf16 each); rows 0-63 then 64-127
    int c0 = tid, c1 = tid + 256;
    int a_r0 = min(m0 + (c0 >> 2), M_ - 1), a_c0 = (c0 & 3) * 8;
    int a_r1 = min(m0 + (c1 >> 2), M_ - 1), a_c1 = (c1 & 3) * 8;
    int b_r0 = n0 + (c0 >> 2), b_r1 = n0 + (c1 >> 2);

    f32x4 acc[4][4];
    const f32x4 zero4 = {0.f, 0.f, 0.f, 0.f};
#pragma unroll
    for (int mi = 0; mi < 4; mi++)
#pragma unroll
        for (int ni = 0; ni < 4; ni++) acc[mi][ni] = zero4;

    for (int k0 = 0; k0 < GK; k0 += 32) {
        __syncthreads();
        load_lds16(A + (size_t)a_r0 * GK + k0 + a_c0, &As[w * 512]);
        load_lds16(A + (size_t)a_r1 * GK + k0 + a_c1, &As[2048 + w * 512]);
        load_lds16(W + (size_t)b_r0 * GK + k0 + a_c0, &Bs[w * 512]);
        load_lds16(W + (size_t)b_r1 * GK + k0 + a_c1, &Bs[2048 + w * 512]);
        __syncthreads();
        short8 af[4], bf[4];
#pragma unroll
        for (int mi = 0; mi < 4; mi++)
            af[mi] = *(const short8*)&As[(wr + mi * 16 + l16) * 32 + quad * 8];
#pragma unroll
        for (int ni = 0; ni < 4; ni++)
            bf[ni] = *(const short8*)&Bs[(wc + ni * 16 + l16) * 32 + quad * 8];
#pragma unroll
        for (int mi = 0; mi < 4; mi++)
#pragma unroll
            for (int ni = 0; ni < 4; ni++)
                acc[mi][ni] = __builtin_amdgcn_mfma_f32_16x16x32_bf16(
                    af[mi], bf[ni], acc[mi][ni], 0, 0, 0);
    }

    // epilogue: n-tile [n0+wc, +64) is one head of one of q/k/v
    int which = n0 >> 9;                       // 0=q 1=k 2=v (no straddle)
    int h = ((n0 + wc) >> 6) & 7;
    unsigned short* dst = (which == 0) ? qb : (which == 1) ? kb : vb;
    float sc = (which == 0) ? 0.125f : 1.0f;
#pragma unroll
    for (int mi = 0; mi < 4; mi++)
#pragma unroll
        for (int reg = 0; reg < 4; reg++) {
            int m = m0 + wr + mi * 16 + quad * 4 + reg;
            if (m < M_) {
                int bb = m / N_;
                int i  = m - bb * N_;
                unsigned short* row = dst + ((size_t)(bb * H_ + h) * N_ + i) * HD_;
#pragma unroll
                for (int ni = 0; ni < 4; ni++)
                    row[ni * 16 + l16] = bf16u(acc[mi][ni][reg] * sc);
            }
        }
}

// Proj variant: A = attn-out bf16 [M][512], W = proj_w bf16, +bias -> fp32 out
__global__ __launch_bounds__(256) void gemm_proj_mfma(
        const unsigned short* __restrict__ A, const unsigned short* __restrict__ W,
        const float* __restrict__ bias, float* __restrict__ out) {
    __shared__ __align__(16) unsigned short As[128 * 32];
    __shared__ __align__(16) unsigned short Bs[128 * 32];
    int tid = threadIdx.x;
    int w = tid >> 6, lane = tid & 63;
    int quad = lane >> 4, l16 = lane & 15;
    int m0 = blockIdx.y * 128;
    int n0 = blockIdx.x * 128;
    int wr = (w >> 1) * 64, wc = (w & 1) * 64;

    int c0 = tid, c1 = tid + 256;
    int a_r0 = min(m0 + (c0 >> 2), M_ - 1), a_c0 = (c0 & 3) * 8;
    int a_r1 = min(m0 + (c1 >> 2), M_ - 1), a_c1 = (c1 & 3) * 8;
    int b_r0 = n0 + (c0 >> 2), b_r1 = n0 + (c1 >> 2);

    f32x4 acc[4][4];
    const f32x4 zero4 = {0.f, 0.f, 0.f, 0.f};
#pragma unroll
    for (int mi = 0; mi < 4; mi++)
#pragma unroll
        for (int ni = 0; ni < 4; ni++) acc[mi][ni] = zero4;

    for (int k0 = 0; k0 < GK; k0 += 32) {
        __syncthreads();
        load_lds16(A + (size_t)a_r0 * GK + k0 + a_c0, &As[w * 512]);
        load_lds16(A + (size_t)a_r1 * GK + k0 + a_c1, &As[2048 + w * 512]);
        load_lds16(W + (size_t)b_r0 * GK + k0 + a_c0, &Bs[w * 512]);
        load_lds16(W + (size_t)b_r1 * GK + k0 + a_c1, &Bs[2048 + w * 512]);
        __syncthreads();
        short8 af[4], bf[4];
#pragma unroll
        for (int mi = 0; mi < 4; mi++)
            af[mi] = *(const short8*)&As[(wr + mi * 16 + l16) * 32 + quad * 8];
#pragma unroll
        for (int ni = 0; ni < 4; ni++)
            bf[ni] = *(const short8*)&Bs[(wc + ni * 16 + l16) * 32 + quad * 8];
#pragma unroll
        for (int mi = 0; mi < 4; mi++)
#pragma unroll
            for (int ni = 0; ni < 4; ni++)
                acc[mi][ni] = __builtin_amdgcn_mfma_f32_16x16x32_bf16(
                    af[mi], bf[ni], acc[mi][ni], 0, 0, 0);
    }

    float bvals[4];
#pragma unroll
    for (int ni = 0; ni < 4; ni++) bvals[ni] = bias[n0 + wc + ni * 16 + l16];
#pragma unroll
    for (int mi = 0; mi < 4; mi++)
#pragma unroll
        for (int reg = 0; reg < 4; reg++) {
            int m = m0 + wr + mi * 16 + quad * 4 + reg;
            if (m < M_) {
                float* row = out + (size_t)m * C_ + n0 + wc;
#pragma unroll
                for (int ni = 0; ni < 4; ni++)
                    row[ni * 16 + l16] = acc[mi][ni][reg] + bvals[ni];
            }
        }
}

// ---------------------------------------------------------------------------
// MFMA flash attention. grid = (ceil(N/128), H, B), 512 threads = 8 waves.
// K staged fragment-ordered via global_load_lds; V staged row-major from
// global, transposed into LDS Vt[dim][40] at write time (<=2-way conflicts).
// Output written as bf16 for the proj MFMA GEMM.
// ---------------------------------------------------------------------------
#define TQ 128
#define JC 32
#define VS 40   // Vt row stride (16B-aligned, frag reads ~4-way worst)

__global__ __launch_bounds__(512) void attn_mfma(const unsigned short* __restrict__ qg,
                                                 const unsigned short* __restrict__ kg,
                                                 const unsigned short* __restrict__ vg,
                                                 const float* __restrict__ tab,
                                                 unsigned short* __restrict__ og) {
    __shared__ __align__(16) unsigned short Kf[32 * 64];     // 4 KB
    __shared__ __align__(16) unsigned short Vt[64 * VS];     // 5 KB
    __shared__ __align__(16) unsigned short Pl[8][16 * 32];  // 8 KB
    __shared__ float tabs[1024];                             // 4 KB

    int tid = threadIdx.x;
    int wave = tid >> 6, lane = tid & 63;
    int quad = lane >> 4, l16 = lane & 15;
    int tile = blockIdx.x, h = blockIdx.y, b = blockIdx.z;
    int bh = b * H_ + h;

    const unsigned short* qp = qg + (size_t)bh * N_ * HD_;
    const unsigned short* kp = kg + (size_t)bh * N_ * HD_;
    const unsigned short* vp = vg + (size_t)bh * N_ * HD_;

    for (int t = tid; t < 1024; t += 512) tabs[t] = tab[h * 1024 + t];

    int row_l = tile * TQ + wave * 16 + l16;
    int rowc = min(row_l, N_ - 1);
    short8 qf[2];
    qf[0] = *(const short8*)(qp + (size_t)rowc * HD_ + quad * 8);
    qf[1] = *(const short8*)(qp + (size_t)rowc * HD_ + 32 + quad * 8);

    int r0c = tile * TQ + wave * 16 + quad * 4;
    float m_i[4], l_i[4];
    f32x4 o_acc[4];
    const f32x4 zero4 = {0.f, 0.f, 0.f, 0.f};
#pragma unroll
    for (int r = 0; r < 4; r++) { m_i[r] = -1e30f; l_i[r] = 0.f; o_acc[r] = zero4; }

    for (int j0 = 0; j0 < N_; j0 += JC) {
        __syncthreads();
        if (wave < 4) {
            // K chunk, fragment-ordered lane-linear: chunk t64 -> key t64&31, oct t64>>5
            int t64 = wave * 64 + lane;
            int key = t64 & 31, oct = t64 >> 5;
            int kk = min(j0 + key, N_ - 1);
            load_lds16(kp + (size_t)kk * HD_ + oct * 8, &Kf[wave * 512]);
        } else {
            // V chunk: read [key][dims], write transposed Vt[dim][key]
            int t2 = tid - 256;
            int key = t2 & 31, dbase = (t2 >> 5) * 8;
            int kk = min(j0 + key, N_ - 1);
            uint4 d = *(const uint4*)(vp + (size_t)kk * HD_ + dbase);
            unsigned short e[8];
            *(uint4*)e = d;
#pragma unroll
            for (int j = 0; j < 8; j++)
                Vt[(dbase + j) * VS + key] = e[j];
        }
        __syncthreads();

        // ---- QK^T ----
        f32x4 s[2];
#pragma unroll
        for (int g = 0; g < 2; g++) {
            short8 kb0 = *(const short8*)&Kf[((0 * 4 + quad) * 32 + g * 16 + l16) * 8];
            short8 kb1 = *(const short8*)&Kf[((1 * 4 + quad) * 32 + g * 16 + l16) * 8];
            f32x4 t = __builtin_amdgcn_mfma_f32_16x16x32_bf16(qf[0], kb0, zero4, 0, 0, 0);
            s[g]     = __builtin_amdgcn_mfma_f32_16x16x32_bf16(qf[1], kb1, t,     0, 0, 0);
        }

        // ---- bias + mask ----
#pragma unroll
        for (int g = 0; g < 2; g++) {
            int jj = j0 + g * 16 + l16;
#pragma unroll
            for (int reg = 0; reg < 4; reg++) {
                int r = r0c + reg;
                float bia;
                if (r >= N_ || jj >= N_)      bia = -1e30f;
                else if (r == 0 || jj == 0)   bia = 0.f;
                else {
                    int ri = r - 1, ji = jj - 1;
                    int da = (ri >> 5) - (ji >> 5); da = da < 0 ? -da : da;
                    int db = (ri & 31) - (ji & 31); db = db < 0 ? -db : db;
                    bia = tabs[da * 32 + db];
                }
                s[g][reg] += bia;
            }
        }

        // ---- online softmax ----
        float mc[4];
#pragma unroll
        for (int reg = 0; reg < 4; reg++) mc[reg] = fmaxf(s[0][reg], s[1][reg]);
#pragma unroll
        for (int off = 1; off < 16; off <<= 1)
#pragma unroll
            for (int reg = 0; reg < 4; reg++)
                mc[reg] = fmaxf(mc[reg], __shfl_xor(mc[reg], off));

        float alpha[4];
#pragma unroll
        for (int reg = 0; reg < 4; reg++) {
            float mnew = fmaxf(m_i[reg], mc[reg]);
            alpha[reg] = __expf(m_i[reg] - mnew);
            m_i[reg] = mnew;
        }
        float ps0[4], ps1[4], lsum[4];
#pragma unroll
        for (int reg = 0; reg < 4; reg++) {
            ps0[reg] = __expf(s[0][reg] - m_i[reg]);
            ps1[reg] = __expf(s[1][reg] - m_i[reg]);
            lsum[reg] = ps0[reg] + ps1[reg];
        }
#pragma unroll
        for (int off = 1; off < 16; off <<= 1)
#pragma unroll
            for (int reg = 0; reg < 4; reg++)
                lsum[reg] += __shfl_xor(lsum[reg], off);
#pragma unroll
        for (int reg = 0; reg < 4; reg++)
            l_i[reg] = l_i[reg] * alpha[reg] + lsum[reg];
#pragma unroll
        for (int g2 = 0; g2 < 4; g2++)
#pragma unroll
            for (int reg = 0; reg < 4; reg++)
                o_acc[g2][reg] *= alpha[reg];

        // ---- P round trip (C-layout -> A-layout) ----
        {
            int par = lane & 1;
            int colp = par * 16 + (l16 & ~1);
#pragma unroll
            for (int reg = 0; reg < 4; reg++) {
                float o0 = __shfl_xor(ps0[reg], 1);
                float o1 = __shfl_xor(ps1[reg], 1);
                float va = par ? o1 : ps0[reg];
                float vb = par ? ps1[reg] : o0;
                *(unsigned*)&Pl[wave][(quad * 4 + reg) * 32 + colp] = pack_bf16x2(va, vb);
            }
        }
        short8 pf = *(const short8*)&Pl[wave][l16 * 32 + quad * 8];

        // ---- PV ----
#pragma unroll
        for (int g2 = 0; g2 < 4; g2++) {
            short8 vb = *(const short8*)&Vt[(g2 * 16 + l16) * VS + quad * 8];
            o_acc[g2] = __builtin_amdgcn_mfma_f32_16x16x32_bf16(pf, vb, o_acc[g2], 0, 0, 0);
        }
    }

    // ---- store bf16 (C-layout) ----
#pragma unroll
    for (int reg = 0; reg < 4; reg++) {
        int r = r0c + reg;
        if (r < N_) {
            float inv = 1.0f / l_i[reg];
            unsigned short* orow = og + ((size_t)b * N_ + r) * C_ + h * HD_ + l16;
#pragma unroll
            for (int g2 = 0; g2 < 4; g2++)
                orow[g2 * 16] = bf16u(o_acc[g2][reg] * inv);
        }
    }
}

// ---------------------------------------------------------------------------
extern "C" void kernel_launch(void* const* d_in, const int* in_sizes, int n_in,
                              void* d_out, int out_size, void* d_ws, size_t ws_size,
                              hipStream_t stream) {
    const float* x      = (const float*)d_in[0];
    const float* qkv_w  = (const float*)d_in[1];
    const float* proj_w = (const float*)d_in[2];
    const float* proj_b = (const float*)d_in[3];
    const float* wg_w   = (const float*)d_in[4];
    const float* wg_b   = (const float*)d_in[5];
    float* out = (float*)d_out;

    const size_t per = (size_t)B_ * H_ * N_ * HD_;   // 4,198,400 elems
    char* ws = (char*)d_ws;
    float* tab            = (float*)ws;                          // 32 KB
    unsigned short* xb    = (unsigned short*)(ws + (32 << 10));
    unsigned short* wqkvb = xb + per;                            // 1536*512
    unsigned short* wprjb = wqkvb + (size_t)3 * C_ * C_;         // 512*512
    unsigned short* qb    = wprjb + (size_t)C_ * C_;
    unsigned short* kb    = qb + per;
    unsigned short* vb    = kb + per;
    unsigned short* ob    = vb + per;                            // [B][N][C] bf16

    bias_tab_kernel<<<32, 256, 0, stream>>>(wg_w, wg_b, tab);
    cast_bf16_kernel<<<(int)(per / 4 / 256), 256, 0, stream>>>(x, xb, (int)per);
    cast_bf16_kernel<<<(3 * C_ * C_) / 4 / 256, 256, 0, stream>>>(qkv_w, wqkvb, 3 * C_ * C_);
    cast_bf16_kernel<<<(C_ * C_) / 4 / 256, 256, 0, stream>>>(proj_w, wprjb, C_ * C_);
    gemm_qkv_mfma<<<dim3(12, 65), 256, 0, stream>>>(xb, wqkvb, qb, kb, vb);
    attn_mfma<<<dim3((N_ + TQ - 1) / TQ, H_, B_), 512, 0, stream>>>(qb, kb, vb, tab, ob);
    gemm_proj_mfma<<<dim3(4, 65), 256, 0, stream>>>(ob, wprjb, proj_b, out);
}

// Round 4
// 279.837 us; speedup vs baseline: 4.0093x; 1.0563x over previous
//
#include <hip/hip_runtime.h>
#include <hip/hip_bf16.h>
#include <math.h>

#define B_  8
#define N_  1025
#define C_  512
#define H_  8
#define HD_ 64
#define M_  (B_ * N_)   // 8200
#define NCH 33          // ceil(N_/32) key chunks
#define VCS 2560        // shorts per vtc chunk: 64 dims * 40 (32 keys + 8 pad)

typedef __attribute__((ext_vector_type(8))) short short8;
typedef __attribute__((ext_vector_type(4))) float f32x4;

__device__ inline unsigned short bf16u(float x) {
    __hip_bfloat16 t = __float2bfloat16(x);
    return *(unsigned short*)&t;
}
__device__ inline unsigned pack_bf16x2(float lo, float hi) {
    return ((unsigned)bf16u(hi) << 16) | bf16u(lo);
}
__device__ inline void load_lds16(const void* g, void* l) {
    __builtin_amdgcn_global_load_lds(
        (const __attribute__((address_space(1))) unsigned int*)g,
        (__attribute__((address_space(3))) unsigned int*)l, 16, 0, 0);
}

// ---------------------------------------------------------------------------
__global__ void cast_bf16_kernel(const float* __restrict__ src,
                                 unsigned short* __restrict__ dst, int n) {
    int i4 = (blockIdx.x * blockDim.x + threadIdx.x) * 4;
    if (i4 + 3 < n) {
        float4 v = *(const float4*)(src + i4);
        ushort4 p;
        p.x = bf16u(v.x); p.y = bf16u(v.y); p.z = bf16u(v.z); p.w = bf16u(v.w);
        *(ushort4*)(dst + i4) = p;
    }
}

// ---------------------------------------------------------------------------
// Geometry bias collapses to an H x 32 x 32 table (dw=dh=0; |dpx|,|dpy| only).
// ---------------------------------------------------------------------------
__global__ void bias_tab_kernel(const float* __restrict__ wg_w,
                                const float* __restrict__ wg_b,
                                float* __restrict__ tab) {
    int idx = blockIdx.x * blockDim.x + threadIdx.x;
    if (idx >= H_ * 32 * 32) return;
    int h = idx >> 10;
    int a = (idx >> 5) & 31;
    int b = idx & 31;
    float dx = logf(fmaxf((float)a * (1.0f / 33.0f), 0.001f));
    float dy = logf(fmaxf((float)b * (1.0f / 33.0f), 0.001f));
    const float* w = wg_w + h * 64;
    float acc = wg_b[h];
#pragma unroll
    for (int k = 0; k < 8; k++) {
        float f = powf(1000.0f, -(float)k * 0.125f);
        float X = 100.0f * dx * f;
        float Y = 100.0f * dy * f;
        acc += w[k]      * sinf(X);
        acc += w[8 + k]  * sinf(Y);
        acc += w[32 + k] * cosf(X);
        acc += w[40 + k] * cosf(Y);
        acc += w[48 + k] + w[56 + k];
    }
    tab[idx] = logf(fmaxf(fmaxf(acc, 0.0f), 1e-6f));
}

// ---------------------------------------------------------------------------
// MFMA GEMM, 128x128 tile, BK=32, 4 waves. QKV variant scatters q (x0.125)
// and k to [bh][tok][64]; v goes to chunk-padded transposed vtc
// [bh][chunk][dim][40] so attention can stage it with global_load_lds.
// ---------------------------------------------------------------------------
#define GK 512

__global__ __launch_bounds__(256) void gemm_qkv_mfma(
        const unsigned short* __restrict__ A, const unsigned short* __restrict__ W,
        unsigned short* __restrict__ qb, unsigned short* __restrict__ kb,
        unsigned short* __restrict__ vtc) {
    __shared__ __align__(16) unsigned short As[128 * 32];
    __shared__ __align__(16) unsigned short Bs[128 * 32];
    int tid = threadIdx.x;
    int w = tid >> 6, lane = tid & 63;
    int quad = lane >> 4, l16 = lane & 15;
    int m0 = blockIdx.y * 128;
    int n0 = blockIdx.x * 128;
    int wr = (w >> 1) * 64, wc = (w & 1) * 64;

    int c0 = tid, c1 = tid + 256;
    int a_r0 = min(m0 + (c0 >> 2), M_ - 1), a_c0 = (c0 & 3) * 8;
    int a_r1 = min(m0 + (c1 >> 2), M_ - 1), a_c1 = (c1 & 3) * 8;
    int b_r0 = n0 + (c0 >> 2), b_r1 = n0 + (c1 >> 2);

    f32x4 acc[4][4];
    const f32x4 zero4 = {0.f, 0.f, 0.f, 0.f};
#pragma unroll
    for (int mi = 0; mi < 4; mi++)
#pragma unroll
        for (int ni = 0; ni < 4; ni++) acc[mi][ni] = zero4;

    for (int k0 = 0; k0 < GK; k0 += 32) {
        __syncthreads();
        load_lds16(A + (size_t)a_r0 * GK + k0 + a_c0, &As[w * 512]);
        load_lds16(A + (size_t)a_r1 * GK + k0 + a_c1, &As[2048 + w * 512]);
        load_lds16(W + (size_t)b_r0 * GK + k0 + a_c0, &Bs[w * 512]);
        load_lds16(W + (size_t)b_r1 * GK + k0 + a_c1, &Bs[2048 + w * 512]);
        __syncthreads();
        short8 af[4], bf[4];
#pragma unroll
        for (int mi = 0; mi < 4; mi++)
            af[mi] = *(const short8*)&As[(wr + mi * 16 + l16) * 32 + quad * 8];
#pragma unroll
        for (int ni = 0; ni < 4; ni++)
            bf[ni] = *(const short8*)&Bs[(wc + ni * 16 + l16) * 32 + quad * 8];
#pragma unroll
        for (int mi = 0; mi < 4; mi++)
#pragma unroll
            for (int ni = 0; ni < 4; ni++)
                acc[mi][ni] = __builtin_amdgcn_mfma_f32_16x16x32_bf16(
                    af[mi], bf[ni], acc[mi][ni], 0, 0, 0);
    }

    int which = n0 >> 9;                       // 0=q 1=k 2=v
    int h = ((n0 + wc) >> 6) & 7;
    if (which < 2) {
        unsigned short* dst = (which == 0) ? qb : kb;
        float sc = (which == 0) ? 0.125f : 1.0f;
#pragma unroll
        for (int mi = 0; mi < 4; mi++)
#pragma unroll
            for (int reg = 0; reg < 4; reg++) {
                int m = m0 + wr + mi * 16 + quad * 4 + reg;
                if (m < M_) {
                    int bb = m / N_;
                    int i  = m - bb * N_;
                    unsigned short* row = dst + ((size_t)(bb * H_ + h) * N_ + i) * HD_;
#pragma unroll
                    for (int ni = 0; ni < 4; ni++)
                        row[ni * 16 + l16] = bf16u(acc[mi][ni][reg] * sc);
                }
            }
    } else {
#pragma unroll
        for (int mi = 0; mi < 4; mi++)
#pragma unroll
            for (int reg = 0; reg < 4; reg++) {
                int m = m0 + wr + mi * 16 + quad * 4 + reg;
                if (m < M_) {
                    int bb = m / N_;
                    int i  = m - bb * N_;
                    int ch = i >> 5, key = i & 31;
                    size_t base = ((size_t)(bb * H_ + h) * NCH + ch) * VCS + key;
#pragma unroll
                    for (int ni = 0; ni < 4; ni++)
                        vtc[base + (size_t)(ni * 16 + l16) * 40] = bf16u(acc[mi][ni][reg]);
                }
            }
    }
}

__global__ __launch_bounds__(256) void gemm_proj_mfma(
        const unsigned short* __restrict__ A, const unsigned short* __restrict__ W,
        const float* __restrict__ bias, float* __restrict__ out) {
    __shared__ __align__(16) unsigned short As[128 * 32];
    __shared__ __align__(16) unsigned short Bs[128 * 32];
    int tid = threadIdx.x;
    int w = tid >> 6, lane = tid & 63;
    int quad = lane >> 4, l16 = lane & 15;
    int m0 = blockIdx.y * 128;
    int n0 = blockIdx.x * 128;
    int wr = (w >> 1) * 64, wc = (w & 1) * 64;

    int c0 = tid, c1 = tid + 256;
    int a_r0 = min(m0 + (c0 >> 2), M_ - 1), a_c0 = (c0 & 3) * 8;
    int a_r1 = min(m0 + (c1 >> 2), M_ - 1), a_c1 = (c1 & 3) * 8;
    int b_r0 = n0 + (c0 >> 2), b_r1 = n0 + (c1 >> 2);

    f32x4 acc[4][4];
    const f32x4 zero4 = {0.f, 0.f, 0.f, 0.f};
#pragma unroll
    for (int mi = 0; mi < 4; mi++)
#pragma unroll
        for (int ni = 0; ni < 4; ni++) acc[mi][ni] = zero4;

    for (int k0 = 0; k0 < GK; k0 += 32) {
        __syncthreads();
        load_lds16(A + (size_t)a_r0 * GK + k0 + a_c0, &As[w * 512]);
        load_lds16(A + (size_t)a_r1 * GK + k0 + a_c1, &As[2048 + w * 512]);
        load_lds16(W + (size_t)b_r0 * GK + k0 + a_c0, &Bs[w * 512]);
        load_lds16(W + (size_t)b_r1 * GK + k0 + a_c1, &Bs[2048 + w * 512]);
        __syncthreads();
        short8 af[4], bf[4];
#pragma unroll
        for (int mi = 0; mi < 4; mi++)
            af[mi] = *(const short8*)&As[(wr + mi * 16 + l16) * 32 + quad * 8];
#pragma unroll
        for (int ni = 0; ni < 4; ni++)
            bf[ni] = *(const short8*)&Bs[(wc + ni * 16 + l16) * 32 + quad * 8];
#pragma unroll
        for (int mi = 0; mi < 4; mi++)
#pragma unroll
            for (int ni = 0; ni < 4; ni++)
                acc[mi][ni] = __builtin_amdgcn_mfma_f32_16x16x32_bf16(
                    af[mi], bf[ni], acc[mi][ni], 0, 0, 0);
    }

    float bvals[4];
#pragma unroll
    for (int ni = 0; ni < 4; ni++) bvals[ni] = bias[n0 + wc + ni * 16 + l16];
#pragma unroll
    for (int mi = 0; mi < 4; mi++)
#pragma unroll
        for (int reg = 0; reg < 4; reg++) {
            int m = m0 + wr + mi * 16 + quad * 4 + reg;
            if (m < M_) {
                float* row = out + (size_t)m * C_ + n0 + wc;
#pragma unroll
                for (int ni = 0; ni < 4; ni++)
                    row[ni * 16 + l16] = acc[mi][ni][reg] + bvals[ni];
            }
        }
}

// ---------------------------------------------------------------------------
// MFMA flash attention, double-buffered cross-barrier prefetch.
// grid = (17, H, B), 256 threads = 4 waves, each wave owns 16 q-rows.
// One barrier per K-chunk: after the barrier, issue chunk i+1 loads
// (global_load_lds -> spare buffer), then compute chunk i. K staged
// fragment-ordered; V staged verbatim from chunk-padded global vtc.
// ---------------------------------------------------------------------------
#define TQ 64

__global__ __launch_bounds__(256) void attn_mfma(const unsigned short* __restrict__ qg,
                                                 const unsigned short* __restrict__ kg,
                                                 const unsigned short* __restrict__ vtc,
                                                 const float* __restrict__ tab,
                                                 unsigned short* __restrict__ og) {
    __shared__ __align__(16) unsigned short Kf[2][2048];   // 8 KB
    __shared__ __align__(16) unsigned short Vt[2][2560];   // 10 KB ([dim][40])
    __shared__ __align__(16) unsigned short Pl[4][640];    // 5 KB  ([16][40])
    __shared__ float tabs[1024];                           // 4 KB

    int tid = threadIdx.x;
    int wave = tid >> 6, lane = tid & 63;
    int quad = lane >> 4, l16 = lane & 15;
    int tile = blockIdx.x, h = blockIdx.y, b = blockIdx.z;
    int bh = b * H_ + h;

    const unsigned short* qp = qg + (size_t)bh * N_ * HD_;
    const unsigned short* kp = kg + (size_t)bh * N_ * HD_;
    const unsigned short* vp = vtc + (size_t)bh * NCH * VCS;

    for (int t = tid; t < 1024; t += 256) tabs[t] = tab[h * 1024 + t];

    int row_l = tile * TQ + wave * 16 + l16;
    int rowc = min(row_l, N_ - 1);
    short8 qf[2];
    qf[0] = *(const short8*)(qp + (size_t)rowc * HD_ + quad * 8);
    qf[1] = *(const short8*)(qp + (size_t)rowc * HD_ + 32 + quad * 8);

    int r0c = tile * TQ + wave * 16 + quad * 4;
    float m_i[4], l_i[4];
    f32x4 o_acc[4];
    const f32x4 zero4 = {0.f, 0.f, 0.f, 0.f};
#pragma unroll
    for (int r = 0; r < 4; r++) { m_i[r] = -1e30f; l_i[r] = 0.f; o_acc[r] = zero4; }

    int skey = tid & 31, soct = tid >> 5;
    auto stage = [&](int c, int buf) {
        int kk = min(c * 32 + skey, N_ - 1);
        load_lds16(kp + (size_t)kk * HD_ + soct * 8, &Kf[buf][wave * 512]);
        const unsigned short* vc = vp + (size_t)c * VCS;
        load_lds16(vc + tid * 8, &Vt[buf][wave * 512]);
        if (wave == 0) load_lds16(vc + 2048 + lane * 8, &Vt[buf][2048]);
    };

    stage(0, 0);

    for (int c = 0; c < NCH; c++) {
        int cur = c & 1;
        int j0 = c * 32;
        __syncthreads();                 // buf[cur] ready; buf[cur^1] free
        if (c + 1 < NCH) stage(c + 1, cur ^ 1);

        // ---- QK^T ----
        f32x4 s[2];
#pragma unroll
        for (int g = 0; g < 2; g++) {
            short8 kb0 = *(const short8*)&Kf[cur][((0 * 4 + quad) * 32 + g * 16 + l16) * 8];
            short8 kb1 = *(const short8*)&Kf[cur][((1 * 4 + quad) * 32 + g * 16 + l16) * 8];
            f32x4 t = __builtin_amdgcn_mfma_f32_16x16x32_bf16(qf[0], kb0, zero4, 0, 0, 0);
            s[g]     = __builtin_amdgcn_mfma_f32_16x16x32_bf16(qf[1], kb1, t,     0, 0, 0);
        }

        // ---- bias + mask ----
#pragma unroll
        for (int g = 0; g < 2; g++) {
            int jj = j0 + g * 16 + l16;
            int ji = jj - 1;
            int pxj = ji >> 5, pyj = ji & 31;
#pragma unroll
            for (int reg = 0; reg < 4; reg++) {
                int r = r0c + reg;
                float bia;
                if (r >= N_ || jj >= N_)      bia = -1e30f;
                else if (r == 0 || jj == 0)   bia = 0.f;
                else {
                    int ri = r - 1;
                    int da = (ri >> 5) - pxj; da = da < 0 ? -da : da;
                    int db = (ri & 31) - pyj; db = db < 0 ? -db : db;
                    bia = tabs[da * 32 + db];
                }
                s[g][reg] += bia;
            }
        }

        // ---- online softmax ----
        float mc[4];
#pragma unroll
        for (int reg = 0; reg < 4; reg++) mc[reg] = fmaxf(s[0][reg], s[1][reg]);
#pragma unroll
        for (int off = 1; off < 16; off <<= 1)
#pragma unroll
            for (int reg = 0; reg < 4; reg++)
                mc[reg] = fmaxf(mc[reg], __shfl_xor(mc[reg], off));

        float alpha[4];
#pragma unroll
        for (int reg = 0; reg < 4; reg++) {
            float mnew = fmaxf(m_i[reg], mc[reg]);
            alpha[reg] = __expf(m_i[reg] - mnew);
            m_i[reg] = mnew;
        }
        float ps0[4], ps1[4], lsum[4];
#pragma unroll
        for (int reg = 0; reg < 4; reg++) {
            ps0[reg] = __expf(s[0][reg] - m_i[reg]);
            ps1[reg] = __expf(s[1][reg] - m_i[reg]);
            lsum[reg] = ps0[reg] + ps1[reg];
        }
#pragma unroll
        for (int off = 1; off < 16; off <<= 1)
#pragma unroll
            for (int reg = 0; reg < 4; reg++)
                lsum[reg] += __shfl_xor(lsum[reg], off);
#pragma unroll
        for (int reg = 0; reg < 4; reg++)
            l_i[reg] = l_i[reg] * alpha[reg] + lsum[reg];
#pragma unroll
        for (int g2 = 0; g2 < 4; g2++)
#pragma unroll
            for (int reg = 0; reg < 4; reg++)
                o_acc[g2][reg] *= alpha[reg];

        // ---- P round trip (C-layout -> A-layout), stride 40 ----
        {
            int par = lane & 1;
            int colp = par * 16 + (l16 & ~1);
#pragma unroll
            for (int reg = 0; reg < 4; reg++) {
                float o0 = __shfl_xor(ps0[reg], 1);
                float o1 = __shfl_xor(ps1[reg], 1);
                float va = par ? o1 : ps0[reg];
                float vb = par ? ps1[reg] : o0;
                *(unsigned*)&Pl[wave][(quad * 4 + reg) * 40 + colp] = pack_bf16x2(va, vb);
            }
        }
        short8 pf = *(const short8*)&Pl[wave][l16 * 40 + quad * 8];

        // ---- PV ----
#pragma unroll
        for (int g2 = 0; g2 < 4; g2++) {
            short8 vb = *(const short8*)&Vt[cur][(g2 * 16 + l16) * 40 + quad * 8];
            o_acc[g2] = __builtin_amdgcn_mfma_f32_16x16x32_bf16(pf, vb, o_acc[g2], 0, 0, 0);
        }
    }

    // ---- store bf16 (C-layout) ----
#pragma unroll
    for (int reg = 0; reg < 4; reg++) {
        int r = r0c + reg;
        if (r < N_) {
            float inv = 1.0f / l_i[reg];
            unsigned short* orow = og + ((size_t)b * N_ + r) * C_ + h * HD_ + l16;
#pragma unroll
            for (int g2 = 0; g2 < 4; g2++)
                orow[g2 * 16] = bf16u(o_acc[g2][reg] * inv);
        }
    }
}

// ---------------------------------------------------------------------------
extern "C" void kernel_launch(void* const* d_in, const int* in_sizes, int n_in,
                              void* d_out, int out_size, void* d_ws, size_t ws_size,
                              hipStream_t stream) {
    const float* x      = (const float*)d_in[0];
    const float* qkv_w  = (const float*)d_in[1];
    const float* proj_w = (const float*)d_in[2];
    const float* proj_b = (const float*)d_in[3];
    const float* wg_w   = (const float*)d_in[4];
    const float* wg_b   = (const float*)d_in[5];
    float* out = (float*)d_out;

    const size_t per = (size_t)B_ * H_ * N_ * HD_;   // 4,198,400 elems
    char* ws = (char*)d_ws;
    float* tab            = (float*)ws;                          // 32 KB
    unsigned short* xb    = (unsigned short*)(ws + (32 << 10));
    unsigned short* wqkvb = xb + per;
    unsigned short* wprjb = wqkvb + (size_t)3 * C_ * C_;
    unsigned short* qb    = wprjb + (size_t)C_ * C_;
    unsigned short* kb    = qb + per;
    unsigned short* vtc   = kb + per;                            // chunk-padded V^T
    unsigned short* ob    = vtc + (size_t)B_ * H_ * NCH * VCS;   // [B][N][C] bf16

    bias_tab_kernel<<<32, 256, 0, stream>>>(wg_w, wg_b, tab);
    cast_bf16_kernel<<<(int)(per / 4 / 256), 256, 0, stream>>>(x, xb, (int)per);
    cast_bf16_kernel<<<(3 * C_ * C_) / 4 / 256, 256, 0, stream>>>(qkv_w, wqkvb, 3 * C_ * C_);
    cast_bf16_kernel<<<(C_ * C_) / 4 / 256, 256, 0, stream>>>(proj_w, wprjb, C_ * C_);
    gemm_qkv_mfma<<<dim3(12, 65), 256, 0, stream>>>(xb, wqkvb, qb, kb, vtc);
    attn_mfma<<<dim3((N_ + TQ - 1) / TQ, H_, B_), 256, 0, stream>>>(qb, kb, vtc, tab, ob);
    gemm_proj_mfma<<<dim3(4, 65), 256, 0, stream>>>(ob, wprjb, proj_b, out);
}

// Round 5
// 272.999 us; speedup vs baseline: 4.1097x; 1.0250x over previous
//
#include <hip/hip_runtime.h>
#include <hip/hip_bf16.h>
#include <math.h>

#define B_  8
#define N_  1025
#define C_  512
#define H_  8
#define HD_ 64
#define M_  (B_ * N_)   // 8200
#define NCH 33          // ceil(N_/32) key chunks
#define VCS 2048        // shorts per vtc chunk: 64 dims * 32 keys

typedef __attribute__((ext_vector_type(8))) short short8;
typedef __attribute__((ext_vector_type(4))) float f32x4;

__device__ inline unsigned short bf16u(float x) {
    __hip_bfloat16 t = __float2bfloat16(x);
    return *(unsigned short*)&t;
}
__device__ inline void load_lds16(const void* g, void* l) {
    __builtin_amdgcn_global_load_lds(
        (const __attribute__((address_space(1))) unsigned int*)g,
        (__attribute__((address_space(3))) unsigned int*)l, 16, 0, 0);
}

// ---------------------------------------------------------------------------
__global__ void cast_bf16_kernel(const float* __restrict__ src,
                                 unsigned short* __restrict__ dst, int n) {
    int i4 = (blockIdx.x * blockDim.x + threadIdx.x) * 4;
    if (i4 + 3 < n) {
        float4 v = *(const float4*)(src + i4);
        ushort4 p;
        p.x = bf16u(v.x); p.y = bf16u(v.y); p.z = bf16u(v.z); p.w = bf16u(v.w);
        *(ushort4*)(dst + i4) = p;
    }
}

// ---------------------------------------------------------------------------
// Geometry bias collapses to an H x 32 x 32 table (dw=dh=0; |dpx|,|dpy| only).
// ---------------------------------------------------------------------------
__global__ void bias_tab_kernel(const float* __restrict__ wg_w,
                                const float* __restrict__ wg_b,
                                float* __restrict__ tab) {
    int idx = blockIdx.x * blockDim.x + threadIdx.x;
    if (idx >= H_ * 32 * 32) return;
    int h = idx >> 10;
    int a = (idx >> 5) & 31;
    int b = idx & 31;
    float dx = logf(fmaxf((float)a * (1.0f / 33.0f), 0.001f));
    float dy = logf(fmaxf((float)b * (1.0f / 33.0f), 0.001f));
    const float* w = wg_w + h * 64;
    float acc = wg_b[h];
#pragma unroll
    for (int k = 0; k < 8; k++) {
        float f = powf(1000.0f, -(float)k * 0.125f);
        float X = 100.0f * dx * f;
        float Y = 100.0f * dy * f;
        acc += w[k]      * sinf(X);
        acc += w[8 + k]  * sinf(Y);
        acc += w[32 + k] * cosf(X);
        acc += w[40 + k] * cosf(Y);
        acc += w[48 + k] + w[56 + k];
    }
    tab[idx] = logf(fmaxf(fmaxf(acc, 0.0f), 1e-6f));
}

// ---------------------------------------------------------------------------
// MFMA GEMM, 128x128 tile, BK=32, 4 waves. QKV variant scatters q (x0.125)
// and k to [bh][tok][64]; v goes to chunk-padded transposed vtc
// [bh][chunk][dim][32].
// ---------------------------------------------------------------------------
#define GK 512

__global__ __launch_bounds__(256) void gemm_qkv_mfma(
        const unsigned short* __restrict__ A, const unsigned short* __restrict__ W,
        unsigned short* __restrict__ qb, unsigned short* __restrict__ kb,
        unsigned short* __restrict__ vtc) {
    __shared__ __align__(16) unsigned short As[128 * 32];
    __shared__ __align__(16) unsigned short Bs[128 * 32];
    int tid = threadIdx.x;
    int w = tid >> 6, lane = tid & 63;
    int quad = lane >> 4, l16 = lane & 15;
    int m0 = blockIdx.y * 128;
    int n0 = blockIdx.x * 128;
    int wr = (w >> 1) * 64, wc = (w & 1) * 64;

    int c0 = tid, c1 = tid + 256;
    int a_r0 = min(m0 + (c0 >> 2), M_ - 1), a_c0 = (c0 & 3) * 8;
    int a_r1 = min(m0 + (c1 >> 2), M_ - 1), a_c1 = (c1 & 3) * 8;
    int b_r0 = n0 + (c0 >> 2), b_r1 = n0 + (c1 >> 2);

    f32x4 acc[4][4];
    const f32x4 zero4 = {0.f, 0.f, 0.f, 0.f};
#pragma unroll
    for (int mi = 0; mi < 4; mi++)
#pragma unroll
        for (int ni = 0; ni < 4; ni++) acc[mi][ni] = zero4;

    for (int k0 = 0; k0 < GK; k0 += 32) {
        __syncthreads();
        load_lds16(A + (size_t)a_r0 * GK + k0 + a_c0, &As[w * 512]);
        load_lds16(A + (size_t)a_r1 * GK + k0 + a_c1, &As[2048 + w * 512]);
        load_lds16(W + (size_t)b_r0 * GK + k0 + a_c0, &Bs[w * 512]);
        load_lds16(W + (size_t)b_r1 * GK + k0 + a_c1, &Bs[2048 + w * 512]);
        __syncthreads();
        short8 af[4], bf[4];
#pragma unroll
        for (int mi = 0; mi < 4; mi++)
            af[mi] = *(const short8*)&As[(wr + mi * 16 + l16) * 32 + quad * 8];
#pragma unroll
        for (int ni = 0; ni < 4; ni++)
            bf[ni] = *(const short8*)&Bs[(wc + ni * 16 + l16) * 32 + quad * 8];
#pragma unroll
        for (int mi = 0; mi < 4; mi++)
#pragma unroll
            for (int ni = 0; ni < 4; ni++)
                acc[mi][ni] = __builtin_amdgcn_mfma_f32_16x16x32_bf16(
                    af[mi], bf[ni], acc[mi][ni], 0, 0, 0);
    }

    int which = n0 >> 9;                       // 0=q 1=k 2=v
    int h = ((n0 + wc) >> 6) & 7;
    if (which < 2) {
        unsigned short* dst = (which == 0) ? qb : kb;
        float sc = (which == 0) ? 0.125f : 1.0f;
#pragma unroll
        for (int mi = 0; mi < 4; mi++)
#pragma unroll
            for (int reg = 0; reg < 4; reg++) {
                int m = m0 + wr + mi * 16 + quad * 4 + reg;
                if (m < M_) {
                    int bb = m / N_;
                    int i  = m - bb * N_;
                    unsigned short* row = dst + ((size_t)(bb * H_ + h) * N_ + i) * HD_;
#pragma unroll
                    for (int ni = 0; ni < 4; ni++)
                        row[ni * 16 + l16] = bf16u(acc[mi][ni][reg] * sc);
                }
            }
    } else {
#pragma unroll
        for (int mi = 0; mi < 4; mi++)
#pragma unroll
            for (int reg = 0; reg < 4; reg++) {
                int m = m0 + wr + mi * 16 + quad * 4 + reg;
                if (m < M_) {
                    int bb = m / N_;
                    int i  = m - bb * N_;
                    int ch = i >> 5, key = i & 31;
                    size_t base = ((size_t)(bb * H_ + h) * NCH + ch) * VCS + key;
#pragma unroll
                    for (int ni = 0; ni < 4; ni++)
                        vtc[base + (size_t)(ni * 16 + l16) * 32] = bf16u(acc[mi][ni][reg]);
                }
            }
    }
}

__global__ __launch_bounds__(256) void gemm_proj_mfma(
        const unsigned short* __restrict__ A, const unsigned short* __restrict__ W,
        const float* __restrict__ bias, float* __restrict__ out) {
    __shared__ __align__(16) unsigned short As[128 * 32];
    __shared__ __align__(16) unsigned short Bs[128 * 32];
    int tid = threadIdx.x;
    int w = tid >> 6, lane = tid & 63;
    int quad = lane >> 4, l16 = lane & 15;
    int m0 = blockIdx.y * 128;
    int n0 = blockIdx.x * 128;
    int wr = (w >> 1) * 64, wc = (w & 1) * 64;

    int c0 = tid, c1 = tid + 256;
    int a_r0 = min(m0 + (c0 >> 2), M_ - 1), a_c0 = (c0 & 3) * 8;
    int a_r1 = min(m0 + (c1 >> 2), M_ - 1), a_c1 = (c1 & 3) * 8;
    int b_r0 = n0 + (c0 >> 2), b_r1 = n0 + (c1 >> 2);

    f32x4 acc[4][4];
    const f32x4 zero4 = {0.f, 0.f, 0.f, 0.f};
#pragma unroll
    for (int mi = 0; mi < 4; mi++)
#pragma unroll
        for (int ni = 0; ni < 4; ni++) acc[mi][ni] = zero4;

    for (int k0 = 0; k0 < GK; k0 += 32) {
        __syncthreads();
        load_lds16(A + (size_t)a_r0 * GK + k0 + a_c0, &As[w * 512]);
        load_lds16(A + (size_t)a_r1 * GK + k0 + a_c1, &As[2048 + w * 512]);
        load_lds16(W + (size_t)b_r0 * GK + k0 + a_c0, &Bs[w * 512]);
        load_lds16(W + (size_t)b_r1 * GK + k0 + a_c1, &Bs[2048 + w * 512]);
        __syncthreads();
        short8 af[4], bf[4];
#pragma unroll
        for (int mi = 0; mi < 4; mi++)
            af[mi] = *(const short8*)&As[(wr + mi * 16 + l16) * 32 + quad * 8];
#pragma unroll
        for (int ni = 0; ni < 4; ni++)
            bf[ni] = *(const short8*)&Bs[(wc + ni * 16 + l16) * 32 + quad * 8];
#pragma unroll
        for (int mi = 0; mi < 4; mi++)
#pragma unroll
            for (int ni = 0; ni < 4; ni++)
                acc[mi][ni] = __builtin_amdgcn_mfma_f32_16x16x32_bf16(
                    af[mi], bf[ni], acc[mi][ni], 0, 0, 0);
    }

    float bvals[4];
#pragma unroll
    for (int ni = 0; ni < 4; ni++) bvals[ni] = bias[n0 + wc + ni * 16 + l16];
#pragma unroll
    for (int mi = 0; mi < 4; mi++)
#pragma unroll
        for (int reg = 0; reg < 4; reg++) {
            int m = m0 + wr + mi * 16 + quad * 4 + reg;
            if (m < M_) {
                float* row = out + (size_t)m * C_ + n0 + wc;
#pragma unroll
                for (int ni = 0; ni < 4; ni++)
                    row[ni * 16 + l16] = acc[mi][ni][reg] + bvals[ni];
            }
        }
}

// ---------------------------------------------------------------------------
// Barrier-free MFMA flash attention, fixed-max softmax.
// grid = (17, H, B), 256 threads = 4 waves; each wave owns 16 q-rows and
// runs all 33 key chunks independently. K fragments double-buffered in
// registers (global prefetch one chunk ahead); V fragments loaded at body
// start, consumed at body end. l accumulated via ones-column MFMA.
// No __syncthreads in the K-loop.
// ---------------------------------------------------------------------------
#define TQ 64

__global__ __launch_bounds__(256) void attn_mfma(const unsigned short* __restrict__ qg,
                                                 const unsigned short* __restrict__ kg,
                                                 const unsigned short* __restrict__ vtc,
                                                 const float* __restrict__ tab,
                                                 unsigned short* __restrict__ og) {
    __shared__ float tabs[34 * 33];                        // stride-33, 4.5 KB
    __shared__ __align__(16) unsigned short Pl[4][16 * 40];// 5 KB, per-wave

    int tid = threadIdx.x;
    int wave = tid >> 6, lane = tid & 63;
    int quad = lane >> 4, l16 = lane & 15;
    int tile = blockIdx.x, h = blockIdx.y, b = blockIdx.z;
    int bh = b * H_ + h;

    const unsigned short* qp = qg + (size_t)bh * N_ * HD_;
    const unsigned short* kp = kg + (size_t)bh * N_ * HD_;
    const unsigned short* vp = vtc + (size_t)bh * NCH * VCS;

    for (int t = tid; t < 1024; t += 256)
        tabs[(t >> 5) * 33 + (t & 31)] = tab[h * 1024 + t];
    __syncthreads();   // tabs ready; only barrier in the kernel

    // Q fragments (A-layout)
    int row_l = tile * TQ + wave * 16 + l16;
    int rowc = min(row_l, N_ - 1);
    short8 qf[2];
    qf[0] = *(const short8*)(qp + (size_t)rowc * HD_ + quad * 8);
    qf[1] = *(const short8*)(qp + (size_t)rowc * HD_ + 32 + quad * 8);

    // C-layout rows owned by this lane; loop-invariant bias terms
    int r0c = tile * TQ + wave * 16 + quad * 4;
    int rpxo[2][4], dbb[2][4];
    bool rz[4];
#pragma unroll
    for (int g = 0; g < 2; g++) {
        int e = g * 16 + l16 - 1;                // ji = c*32 + e
        int pxo = (e < 0) ? -1 : 0;
        int pyj = e & 31;
#pragma unroll
        for (int reg = 0; reg < 4; reg++) {
            int r = r0c + reg;
            int ri = min(max(r - 1, 0), N_ - 2);
            rpxo[g][reg] = (ri >> 5) - pxo;      // da = |rpxo - c|
            int db = (ri & 31) - pyj;
            dbb[g][reg] = (db < 0) ? -db : db;
            if (g == 0) rz[reg] = (r == 0);
        }
    }

    f32x4 o_acc[4], l_acc;
    const f32x4 zero4 = {0.f, 0.f, 0.f, 0.f};
#pragma unroll
    for (int g2 = 0; g2 < 4; g2++) o_acc[g2] = zero4;
    l_acc = zero4;
    short8 ones;
    {
        short one_bf = (short)0x3F80;
#pragma unroll
        for (int j = 0; j < 8; j++) ones[j] = one_bf;
    }

    auto loadK = [&](int c, short8* kf) {
        int k0 = min(c * 32 + l16, N_ - 1);
        int k1 = min(c * 32 + 16 + l16, N_ - 1);
        kf[0] = *(const short8*)(kp + (size_t)k0 * HD_ + quad * 8);
        kf[1] = *(const short8*)(kp + (size_t)k0 * HD_ + 32 + quad * 8);
        kf[2] = *(const short8*)(kp + (size_t)k1 * HD_ + quad * 8);
        kf[3] = *(const short8*)(kp + (size_t)k1 * HD_ + 32 + quad * 8);
    };

    auto body = [&](int c, const short8* kf, bool first, bool last) {
        // V fragments: issue early, consume at end of body
        short8 vf[4];
        const unsigned short* vc = vp + (size_t)c * VCS + quad * 8;
#pragma unroll
        for (int g2 = 0; g2 < 4; g2++)
            vf[g2] = *(const short8*)(vc + (g2 * 16 + l16) * 32);

        // QK^T: S[16 rows][32 keys]
        f32x4 s[2];
        s[0] = __builtin_amdgcn_mfma_f32_16x16x32_bf16(qf[0], kf[0], zero4, 0, 0, 0);
        s[0] = __builtin_amdgcn_mfma_f32_16x16x32_bf16(qf[1], kf[1], s[0], 0, 0, 0);
        s[1] = __builtin_amdgcn_mfma_f32_16x16x32_bf16(qf[0], kf[2], zero4, 0, 0, 0);
        s[1] = __builtin_amdgcn_mfma_f32_16x16x32_bf16(qf[1], kf[3], s[1], 0, 0, 0);

        // bias add (hoisted constants; 1 LDS read per (g,reg))
#pragma unroll
        for (int g = 0; g < 2; g++)
#pragma unroll
            for (int reg = 0; reg < 4; reg++) {
                int da = rpxo[g][reg] - c;
                da = (da < 0) ? -da : da;
                float bia = tabs[da * 33 + dbb[g][reg]];
                if (rz[reg]) bia = 0.f;
                if (first && g == 0 && l16 == 0) bia = 0.f;   // jj == 0 column
                s[g][reg] += bia;
            }
        if (last) {   // keys >= N_ in final chunk
#pragma unroll
            for (int reg = 0; reg < 4; reg++) {
                if (l16 != 0) s[0][reg] = -1e30f;
                s[1][reg] = -1e30f;
            }
        }

        // fixed-max softmax: p = exp(s)
        float p0[4], p1[4];
#pragma unroll
        for (int reg = 0; reg < 4; reg++) {
            p0[reg] = __expf(s[0][reg]);
            p1[reg] = __expf(s[1][reg]);
        }

        // P round trip (C-layout -> A-layout), per-wave LDS, no barrier
        unsigned short* plw = &Pl[wave][0];
#pragma unroll
        for (int reg = 0; reg < 4; reg++) {
            plw[(quad * 4 + reg) * 40 + l16]      = bf16u(p0[reg]);
            plw[(quad * 4 + reg) * 40 + 16 + l16] = bf16u(p1[reg]);
        }
        short8 pf = *(const short8*)&Pl[wave][l16 * 40 + quad * 8];

        // PV + l accumulation (ones-column trick)
#pragma unroll
        for (int g2 = 0; g2 < 4; g2++)
            o_acc[g2] = __builtin_amdgcn_mfma_f32_16x16x32_bf16(pf, vf[g2], o_acc[g2], 0, 0, 0);
        l_acc = __builtin_amdgcn_mfma_f32_16x16x32_bf16(pf, ones, l_acc, 0, 0, 0);
    };

    short8 kfA[4], kfB[4];
    loadK(0, kfA);
    loadK(1, kfB);
    body(0, kfA, true, false);
#pragma unroll 1
    for (int c = 1; c <= 29; c += 2) {
        loadK(c + 1, kfA);
        body(c, kfB, false, false);
        loadK(c + 2, kfB);
        body(c + 1, kfA, false, false);
    }
    loadK(32, kfA);
    body(31, kfB, false, false);
    body(32, kfA, false, true);

    // store bf16 (C-layout)
#pragma unroll
    for (int reg = 0; reg < 4; reg++) {
        int r = r0c + reg;
        if (r < N_) {
            float inv = 1.0f / l_acc[reg];
            unsigned short* orow = og + ((size_t)b * N_ + r) * C_ + h * HD_ + l16;
#pragma unroll
            for (int g2 = 0; g2 < 4; g2++)
                orow[g2 * 16] = bf16u(o_acc[g2][reg] * inv);
        }
    }
}

// ---------------------------------------------------------------------------
extern "C" void kernel_launch(void* const* d_in, const int* in_sizes, int n_in,
                              void* d_out, int out_size, void* d_ws, size_t ws_size,
                              hipStream_t stream) {
    const float* x      = (const float*)d_in[0];
    const float* qkv_w  = (const float*)d_in[1];
    const float* proj_w = (const float*)d_in[2];
    const float* proj_b = (const float*)d_in[3];
    const float* wg_w   = (const float*)d_in[4];
    const float* wg_b   = (const float*)d_in[5];
    float* out = (float*)d_out;

    const size_t per = (size_t)B_ * H_ * N_ * HD_;   // 4,198,400 elems
    char* ws = (char*)d_ws;
    float* tab            = (float*)ws;                          // 32 KB
    unsigned short* xb    = (unsigned short*)(ws + (32 << 10));
    unsigned short* wqkvb = xb + per;
    unsigned short* wprjb = wqkvb + (size_t)3 * C_ * C_;
    unsigned short* qb    = wprjb + (size_t)C_ * C_;
    unsigned short* kb    = qb + per;
    unsigned short* vtc   = kb + per;                            // [bh][ch][dim][32]
    unsigned short* ob    = vtc + (size_t)B_ * H_ * NCH * VCS;   // [B][N][C] bf16

    bias_tab_kernel<<<32, 256, 0, stream>>>(wg_w, wg_b, tab);
    cast_bf16_kernel<<<(int)(per / 4 / 256), 256, 0, stream>>>(x, xb, (int)per);
    cast_bf16_kernel<<<(3 * C_ * C_) / 4 / 256, 256, 0, stream>>>(qkv_w, wqkvb, 3 * C_ * C_);
    cast_bf16_kernel<<<(C_ * C_) / 4 / 256, 256, 0, stream>>>(proj_w, wprjb, C_ * C_);
    gemm_qkv_mfma<<<dim3(12, 65), 256, 0, stream>>>(xb, wqkvb, qb, kb, vtc);
    attn_mfma<<<dim3((N_ + TQ - 1) / TQ, H_, B_), 256, 0, stream>>>(qb, kb, vtc, tab, ob);
    gemm_proj_mfma<<<dim3(4, 65), 256, 0, stream>>>(ob, wprjb, proj_b, out);
}

// Round 6
// 272.046 us; speedup vs baseline: 4.1241x; 1.0035x over previous
//
#include <hip/hip_runtime.h>
#include <hip/hip_bf16.h>
#include <math.h>

#define B_  8
#define N_  1025
#define C_  512
#define H_  8
#define HD_ 64
#define M_  (B_ * N_)   // 8200
#define NCH 33          // ceil(N_/32) key chunks
#define VCS 2048        // shorts per vtc chunk: 64 dims * 32 keys

typedef __attribute__((ext_vector_type(8))) short short8;
typedef __attribute__((ext_vector_type(4))) float f32x4;

__device__ inline unsigned short bf16u(float x) {
    __hip_bfloat16 t = __float2bfloat16(x);
    return *(unsigned short*)&t;
}
__device__ inline void load_lds16(const void* g, void* l) {
    __builtin_amdgcn_global_load_lds(
        (const __attribute__((address_space(1))) unsigned int*)g,
        (__attribute__((address_space(3))) unsigned int*)l, 16, 0, 0);
}

// ---------------------------------------------------------------------------
__global__ void cast_bf16_kernel(const float* __restrict__ src,
                                 unsigned short* __restrict__ dst, int n) {
    int i4 = (blockIdx.x * blockDim.x + threadIdx.x) * 4;
    if (i4 + 3 < n) {
        float4 v = *(const float4*)(src + i4);
        ushort4 p;
        p.x = bf16u(v.x); p.y = bf16u(v.y); p.z = bf16u(v.z); p.w = bf16u(v.w);
        *(ushort4*)(dst + i4) = p;
    }
}

// ---------------------------------------------------------------------------
// Geometry bias collapses to an H x 32 x 32 table (dw=dh=0; |dpx|,|dpy| only).
// ---------------------------------------------------------------------------
__global__ void bias_tab_kernel(const float* __restrict__ wg_w,
                                const float* __restrict__ wg_b,
                                float* __restrict__ tab) {
    int idx = blockIdx.x * blockDim.x + threadIdx.x;
    if (idx >= H_ * 32 * 32) return;
    int h = idx >> 10;
    int a = (idx >> 5) & 31;
    int b = idx & 31;
    float dx = logf(fmaxf((float)a * (1.0f / 33.0f), 0.001f));
    float dy = logf(fmaxf((float)b * (1.0f / 33.0f), 0.001f));
    const float* w = wg_w + h * 64;
    float acc = wg_b[h];
#pragma unroll
    for (int k = 0; k < 8; k++) {
        float f = powf(1000.0f, -(float)k * 0.125f);
        float X = 100.0f * dx * f;
        float Y = 100.0f * dy * f;
        acc += w[k]      * sinf(X);
        acc += w[8 + k]  * sinf(Y);
        acc += w[32 + k] * cosf(X);
        acc += w[40 + k] * cosf(Y);
        acc += w[48 + k] + w[56 + k];
    }
    tab[idx] = logf(fmaxf(fmaxf(acc, 0.0f), 1e-6f));
}

// ---------------------------------------------------------------------------
// MFMA GEMM, 128x128 tile, BK=32, 4 waves. QKV variant scatters q (x0.125)
// and k to [bh][tok][64]; v goes to chunk-padded transposed vtc
// [bh][chunk][dim][32].
// ---------------------------------------------------------------------------
#define GK 512

__global__ __launch_bounds__(256) void gemm_qkv_mfma(
        const unsigned short* __restrict__ A, const unsigned short* __restrict__ W,
        unsigned short* __restrict__ qb, unsigned short* __restrict__ kb,
        unsigned short* __restrict__ vtc) {
    __shared__ __align__(16) unsigned short As[128 * 32];
    __shared__ __align__(16) unsigned short Bs[128 * 32];
    int tid = threadIdx.x;
    int w = tid >> 6, lane = tid & 63;
    int quad = lane >> 4, l16 = lane & 15;
    int m0 = blockIdx.y * 128;
    int n0 = blockIdx.x * 128;
    int wr = (w >> 1) * 64, wc = (w & 1) * 64;

    int c0 = tid, c1 = tid + 256;
    int a_r0 = min(m0 + (c0 >> 2), M_ - 1), a_c0 = (c0 & 3) * 8;
    int a_r1 = min(m0 + (c1 >> 2), M_ - 1), a_c1 = (c1 & 3) * 8;
    int b_r0 = n0 + (c0 >> 2), b_r1 = n0 + (c1 >> 2);

    f32x4 acc[4][4];
    const f32x4 zero4 = {0.f, 0.f, 0.f, 0.f};
#pragma unroll
    for (int mi = 0; mi < 4; mi++)
#pragma unroll
        for (int ni = 0; ni < 4; ni++) acc[mi][ni] = zero4;

    for (int k0 = 0; k0 < GK; k0 += 32) {
        __syncthreads();
        load_lds16(A + (size_t)a_r0 * GK + k0 + a_c0, &As[w * 512]);
        load_lds16(A + (size_t)a_r1 * GK + k0 + a_c1, &As[2048 + w * 512]);
        load_lds16(W + (size_t)b_r0 * GK + k0 + a_c0, &Bs[w * 512]);
        load_lds16(W + (size_t)b_r1 * GK + k0 + a_c1, &Bs[2048 + w * 512]);
        __syncthreads();
        short8 af[4], bf[4];
#pragma unroll
        for (int mi = 0; mi < 4; mi++)
            af[mi] = *(const short8*)&As[(wr + mi * 16 + l16) * 32 + quad * 8];
#pragma unroll
        for (int ni = 0; ni < 4; ni++)
            bf[ni] = *(const short8*)&Bs[(wc + ni * 16 + l16) * 32 + quad * 8];
#pragma unroll
        for (int mi = 0; mi < 4; mi++)
#pragma unroll
            for (int ni = 0; ni < 4; ni++)
                acc[mi][ni] = __builtin_amdgcn_mfma_f32_16x16x32_bf16(
                    af[mi], bf[ni], acc[mi][ni], 0, 0, 0);
    }

    int which = n0 >> 9;                       // 0=q 1=k 2=v
    int h = ((n0 + wc) >> 6) & 7;
    if (which < 2) {
        unsigned short* dst = (which == 0) ? qb : kb;
        float sc = (which == 0) ? 0.125f : 1.0f;
#pragma unroll
        for (int mi = 0; mi < 4; mi++)
#pragma unroll
            for (int reg = 0; reg < 4; reg++) {
                int m = m0 + wr + mi * 16 + quad * 4 + reg;
                if (m < M_) {
                    int bb = m / N_;
                    int i  = m - bb * N_;
                    unsigned short* row = dst + ((size_t)(bb * H_ + h) * N_ + i) * HD_;
#pragma unroll
                    for (int ni = 0; ni < 4; ni++)
                        row[ni * 16 + l16] = bf16u(acc[mi][ni][reg] * sc);
                }
            }
    } else {
#pragma unroll
        for (int mi = 0; mi < 4; mi++)
#pragma unroll
            for (int reg = 0; reg < 4; reg++) {
                int m = m0 + wr + mi * 16 + quad * 4 + reg;
                if (m < M_) {
                    int bb = m / N_;
                    int i  = m - bb * N_;
                    int ch = i >> 5, key = i & 31;
                    size_t base = ((size_t)(bb * H_ + h) * NCH + ch) * VCS + key;
#pragma unroll
                    for (int ni = 0; ni < 4; ni++)
                        vtc[base + (size_t)(ni * 16 + l16) * 32] = bf16u(acc[mi][ni][reg]);
                }
            }
    }
}

__global__ __launch_bounds__(256) void gemm_proj_mfma(
        const unsigned short* __restrict__ A, const unsigned short* __restrict__ W,
        const float* __restrict__ bias, float* __restrict__ out) {
    __shared__ __align__(16) unsigned short As[128 * 32];
    __shared__ __align__(16) unsigned short Bs[128 * 32];
    int tid = threadIdx.x;
    int w = tid >> 6, lane = tid & 63;
    int quad = lane >> 4, l16 = lane & 15;
    int m0 = blockIdx.y * 128;
    int n0 = blockIdx.x * 128;
    int wr = (w >> 1) * 64, wc = (w & 1) * 64;

    int c0 = tid, c1 = tid + 256;
    int a_r0 = min(m0 + (c0 >> 2), M_ - 1), a_c0 = (c0 & 3) * 8;
    int a_r1 = min(m0 + (c1 >> 2), M_ - 1), a_c1 = (c1 & 3) * 8;
    int b_r0 = n0 + (c0 >> 2), b_r1 = n0 + (c1 >> 2);

    f32x4 acc[4][4];
    const f32x4 zero4 = {0.f, 0.f, 0.f, 0.f};
#pragma unroll
    for (int mi = 0; mi < 4; mi++)
#pragma unroll
        for (int ni = 0; ni < 4; ni++) acc[mi][ni] = zero4;

    for (int k0 = 0; k0 < GK; k0 += 32) {
        __syncthreads();
        load_lds16(A + (size_t)a_r0 * GK + k0 + a_c0, &As[w * 512]);
        load_lds16(A + (size_t)a_r1 * GK + k0 + a_c1, &As[2048 + w * 512]);
        load_lds16(W + (size_t)b_r0 * GK + k0 + a_c0, &Bs[w * 512]);
        load_lds16(W + (size_t)b_r1 * GK + k0 + a_c1, &Bs[2048 + w * 512]);
        __syncthreads();
        short8 af[4], bf[4];
#pragma unroll
        for (int mi = 0; mi < 4; mi++)
            af[mi] = *(const short8*)&As[(wr + mi * 16 + l16) * 32 + quad * 8];
#pragma unroll
        for (int ni = 0; ni < 4; ni++)
            bf[ni] = *(const short8*)&Bs[(wc + ni * 16 + l16) * 32 + quad * 8];
#pragma unroll
        for (int mi = 0; mi < 4; mi++)
#pragma unroll
            for (int ni = 0; ni < 4; ni++)
                acc[mi][ni] = __builtin_amdgcn_mfma_f32_16x16x32_bf16(
                    af[mi], bf[ni], acc[mi][ni], 0, 0, 0);
    }

    float bvals[4];
#pragma unroll
    for (int ni = 0; ni < 4; ni++) bvals[ni] = bias[n0 + wc + ni * 16 + l16];
#pragma unroll
    for (int mi = 0; mi < 4; mi++)
#pragma unroll
        for (int reg = 0; reg < 4; reg++) {
            int m = m0 + wr + mi * 16 + quad * 4 + reg;
            if (m < M_) {
                float* row = out + (size_t)m * C_ + n0 + wc;
#pragma unroll
                for (int ni = 0; ni < 4; ni++)
                    row[ni * 16 + l16] = acc[mi][ni][reg] + bvals[ni];
            }
        }
}

// ---------------------------------------------------------------------------
// Barrier-free MFMA flash attention, fixed-max softmax, XCD-swizzled grid.
// 1-D grid of 1088 blocks decoded so all 17 tiles of one (b,h) share
// blockIdx%8 (-> same XCD, K/V stay L2-resident: 8 bh x 262 KB = 2.1 MB/XCD).
// K register-double-buffered with depth-2 prefetch (issued right after QK
// consumes the buffer, ~2 bodies before use); V double-buffered depth-1.
// l accumulated via ones-column MFMA. No __syncthreads in the K-loop.
// ---------------------------------------------------------------------------
#define TQ 64

__global__ __launch_bounds__(256) void attn_mfma(const unsigned short* __restrict__ qg,
                                                 const unsigned short* __restrict__ kg,
                                                 const unsigned short* __restrict__ vtc,
                                                 const float* __restrict__ tab,
                                                 unsigned short* __restrict__ og) {
    __shared__ float tabs[34 * 33];                        // stride-33, 4.5 KB
    __shared__ __align__(16) unsigned short Pl[4][16 * 40];// 5 KB, per-wave

    int tid = threadIdx.x;
    int wave = tid >> 6, lane = tid & 63;
    int quad = lane >> 4, l16 = lane & 15;

    // XCD swizzle: lin = xcd + 8*(bhi + 8*tile); all tiles of bh share lin%8
    int lin = blockIdx.x;
    int xcd = lin & 7;
    int slot = lin >> 3;
    int tile = slot >> 3;
    int bh = xcd * 8 + (slot & 7);
    int b = bh >> 3, h = bh & 7;

    const unsigned short* qp = qg + (size_t)bh * N_ * HD_;
    const unsigned short* kp = kg + (size_t)bh * N_ * HD_;
    const unsigned short* vp = vtc + (size_t)bh * NCH * VCS;

    for (int t = tid; t < 1024; t += 256)
        tabs[(t >> 5) * 33 + (t & 31)] = tab[h * 1024 + t];
    __syncthreads();   // tabs ready; only barrier in the kernel

    // Q fragments (A-layout)
    int row_l = tile * TQ + wave * 16 + l16;
    int rowc = min(row_l, N_ - 1);
    short8 qf[2];
    qf[0] = *(const short8*)(qp + (size_t)rowc * HD_ + quad * 8);
    qf[1] = *(const short8*)(qp + (size_t)rowc * HD_ + 32 + quad * 8);

    // C-layout rows owned by this lane; loop-invariant bias terms
    int r0c = tile * TQ + wave * 16 + quad * 4;
    int rpx[2][4], dbb[2][4];
    bool rz[4];
#pragma unroll
    for (int g = 0; g < 2; g++) {
        int e = g * 16 + l16 - 1;                // ji = c*32 + e
        int pxo = (e < 0) ? -1 : 0;
        int pyj = e & 31;
#pragma unroll
        for (int reg = 0; reg < 4; reg++) {
            int r = r0c + reg;
            int ri = min(max(r - 1, 0), N_ - 2);
            rpx[g][reg] = (ri >> 5) - pxo;       // da = |rpx - c|
            int db = (ri & 31) - pyj;
            dbb[g][reg] = (db < 0) ? -db : db;
            if (g == 0) rz[reg] = (r == 0);
        }
    }

    f32x4 o_acc[4], l_acc;
    const f32x4 zero4 = {0.f, 0.f, 0.f, 0.f};
#pragma unroll
    for (int g2 = 0; g2 < 4; g2++) o_acc[g2] = zero4;
    l_acc = zero4;
    short8 ones;
    {
        short one_bf = (short)0x3F80;
#pragma unroll
        for (int j = 0; j < 8; j++) ones[j] = one_bf;
    }

    auto loadK = [&](int c, short8* kf) {
        int k0 = min(c * 32 + l16, N_ - 1);
        int k1 = min(c * 32 + 16 + l16, N_ - 1);
        kf[0] = *(const short8*)(kp + (size_t)k0 * HD_ + quad * 8);
        kf[1] = *(const short8*)(kp + (size_t)k0 * HD_ + 32 + quad * 8);
        kf[2] = *(const short8*)(kp + (size_t)k1 * HD_ + quad * 8);
        kf[3] = *(const short8*)(kp + (size_t)k1 * HD_ + 32 + quad * 8);
    };
    auto loadV = [&](int c, short8* vf) {
        const unsigned short* vc = vp + (size_t)c * VCS + quad * 8;
#pragma unroll
        for (int g2 = 0; g2 < 4; g2++)
            vf[g2] = *(const short8*)(vc + (g2 * 16 + l16) * 32);
    };

    auto body = [&](int c, const short8* kf, const short8* vf,
                    short8* kpre, short8* vpre, bool prefK, bool prefV,
                    bool first, bool last) {
        // QK^T consumes kf -> its buffer is immediately reloadable
        f32x4 s[2];
        s[0] = __builtin_amdgcn_mfma_f32_16x16x32_bf16(qf[0], kf[0], zero4, 0, 0, 0);
        s[0] = __builtin_amdgcn_mfma_f32_16x16x32_bf16(qf[1], kf[1], s[0], 0, 0, 0);
        s[1] = __builtin_amdgcn_mfma_f32_16x16x32_bf16(qf[0], kf[2], zero4, 0, 0, 0);
        s[1] = __builtin_amdgcn_mfma_f32_16x16x32_bf16(qf[1], kf[3], s[1], 0, 0, 0);
        if (prefK) loadK(c + 2, kpre);      // used 2 bodies from now

        // bias add: idx = |rpx - c|*33 + dbb  (sad + mad + ds_read)
#pragma unroll
        for (int g = 0; g < 2; g++)
#pragma unroll
            for (int reg = 0; reg < 4; reg++) {
                int da = __sad(rpx[g][reg], c, 0u);
                float bia = tabs[da * 33 + dbb[g][reg]];
                if (rz[reg]) bia = 0.f;
                if (first && g == 0 && l16 == 0) bia = 0.f;   // jj == 0 column
                s[g][reg] += bia;
            }
        if (prefV) loadV(c + 1, vpre);      // used at end of next body
        if (last) {   // keys >= N_ in final chunk
#pragma unroll
            for (int reg = 0; reg < 4; reg++) {
                if (l16 != 0) s[0][reg] = -1e30f;
                s[1][reg] = -1e30f;
            }
        }

        // fixed-max softmax: p = exp(s)
        float p0[4], p1[4];
#pragma unroll
        for (int reg = 0; reg < 4; reg++) {
            p0[reg] = __expf(s[0][reg]);
            p1[reg] = __expf(s[1][reg]);
        }

        // P round trip (C-layout -> A-layout), per-wave LDS, no barrier
        unsigned short* plw = &Pl[wave][0];
#pragma unroll
        for (int reg = 0; reg < 4; reg++) {
            plw[(quad * 4 + reg) * 40 + l16]      = bf16u(p0[reg]);
            plw[(quad * 4 + reg) * 40 + 16 + l16] = bf16u(p1[reg]);
        }
        short8 pf = *(const short8*)&Pl[wave][l16 * 40 + quad * 8];

        // PV + l accumulation (ones-column trick)
#pragma unroll
        for (int g2 = 0; g2 < 4; g2++)
            o_acc[g2] = __builtin_amdgcn_mfma_f32_16x16x32_bf16(pf, vf[g2], o_acc[g2], 0, 0, 0);
        l_acc = __builtin_amdgcn_mfma_f32_16x16x32_bf16(pf, ones, l_acc, 0, 0, 0);
    };

    short8 kA[4], kB[4], vA[4], vB[4];
    loadK(0, kA);
    loadK(1, kB);
    loadV(0, vA);
    // chunk c uses K[c&1], V[c&1]; prefK c+2 -> same K buffer; prefV c+1 -> other V buffer
    body(0, kA, vA, kA, vB, true, true, true, false);
#pragma unroll 1
    for (int c = 1; c <= 29; c += 2) {
        body(c,     kB, vB, kB, vA, true, true, false, false);
        body(c + 1, kA, vA, kA, vB, true, true, false, false);
    }
    body(31, kB, vB, nullptr, vA, false, true, false, false);  // loadV(32)->vA
    body(32, kA, vA, nullptr, nullptr, false, false, false, true);

    // store bf16 (C-layout)
#pragma unroll
    for (int reg = 0; reg < 4; reg++) {
        int r = r0c + reg;
        if (r < N_) {
            float inv = 1.0f / l_acc[reg];
            unsigned short* orow = og + ((size_t)b * N_ + r) * C_ + h * HD_ + l16;
#pragma unroll
            for (int g2 = 0; g2 < 4; g2++)
                orow[g2 * 16] = bf16u(o_acc[g2][reg] * inv);
        }
    }
}

// ---------------------------------------------------------------------------
extern "C" void kernel_launch(void* const* d_in, const int* in_sizes, int n_in,
                              void* d_out, int out_size, void* d_ws, size_t ws_size,
                              hipStream_t stream) {
    const float* x      = (const float*)d_in[0];
    const float* qkv_w  = (const float*)d_in[1];
    const float* proj_w = (const float*)d_in[2];
    const float* proj_b = (const float*)d_in[3];
    const float* wg_w   = (const float*)d_in[4];
    const float* wg_b   = (const float*)d_in[5];
    float* out = (float*)d_out;

    const size_t per = (size_t)B_ * H_ * N_ * HD_;   // 4,198,400 elems
    char* ws = (char*)d_ws;
    float* tab            = (float*)ws;                          // 32 KB
    unsigned short* xb    = (unsigned short*)(ws + (32 << 10));
    unsigned short* wqkvb = xb + per;
    unsigned short* wprjb = wqkvb + (size_t)3 * C_ * C_;
    unsigned short* qb    = wprjb + (size_t)C_ * C_;
    unsigned short* kb    = qb + per;
    unsigned short* vtc   = kb + per;                            // [bh][ch][dim][32]
    unsigned short* ob    = vtc + (size_t)B_ * H_ * NCH * VCS;   // [B][N][C] bf16

    bias_tab_kernel<<<32, 256, 0, stream>>>(wg_w, wg_b, tab);
    cast_bf16_kernel<<<(int)(per / 4 / 256), 256, 0, stream>>>(x, xb, (int)per);
    cast_bf16_kernel<<<(3 * C_ * C_) / 4 / 256, 256, 0, stream>>>(qkv_w, wqkvb, 3 * C_ * C_);
    cast_bf16_kernel<<<(C_ * C_) / 4 / 256, 256, 0, stream>>>(proj_w, wprjb, C_ * C_);
    gemm_qkv_mfma<<<dim3(12, 65), 256, 0, stream>>>(xb, wqkvb, qb, kb, vtc);
    attn_mfma<<<17 * 8 * 8, 256, 0, stream>>>(qb, kb, vtc, tab, ob);
    gemm_proj_mfma<<<dim3(4, 65), 256, 0, stream>>>(ob, wprjb, proj_b, out);
}